// Round 6
// baseline (932.209 us; speedup 1.0000x reference)
//
#include <hip/hip_runtime.h>

#define NN 20000
#define NE 320000
#define D 128
#define LAYERS 3
#define BN_EPS 1e-5f

typedef __attribute__((ext_vector_type(8))) short s16x8;
typedef __attribute__((ext_vector_type(4))) float f32x4;

// fast sigmoid: v_rcp_f32 instead of IEEE divide sequence (~1 ulp; outputs are
// bf16-rounded immediately so this is far below the accepted tolerance)
__device__ __forceinline__ float sigm_(float x) {
    return __builtin_amdgcn_rcpf(1.0f + __expf(-x));
}
__device__ __forceinline__ float silu_(float x) { return x * sigm_(x); }
__device__ __forceinline__ float bf2f(unsigned short u) {
    union { unsigned int u; float f; } v; v.u = ((unsigned int)u) << 16; return v.f;
}
__device__ __forceinline__ unsigned short f2bf(float f) {
    union { float f; unsigned int u; } v; v.f = f;
    return (unsigned short)((v.u + 0x7FFFu + ((v.u >> 16) & 1u)) >> 16);
}

#define SWT_STRIDE 136

// ---------- all weight conversions in one dispatch: blockIdx.y = job
struct ConvJobs {
    const float* W[17];
    unsigned short* Hi[17];
    unsigned short* Lo[17];  // nullptr => single bf16 convert
};
__global__ __launch_bounds__(256) void conv_all_kernel(ConvJobs jobs)
{
    int y = blockIdx.y;
    int idx = blockIdx.x * 256 + threadIdx.x;  // 16384
    int k = idx >> 7, n = idx & 127;
    float v = jobs.W[y][idx];
    unsigned short hi = f2bf(v);
    jobs.Hi[y][n * 128 + k] = hi;
    if (jobs.Lo[y]) jobs.Lo[y][n * 128 + k] = f2bf(v - bf2f(hi));
}

struct MatsB2 {
    const unsigned short* WThi[4];
    const unsigned short* WTlo[4];
    const float* b[4];
    float* C[4];
};

// ---------- split-precision MFMA node matmul
__global__ __launch_bounds__(256, 2) void mfmm_node_kernel(
    const unsigned short* __restrict__ Ahi, const unsigned short* __restrict__ Alo,
    int M, MatsB2 ms)
{
    __shared__ unsigned short sW[128 * SWT_STRIDE];
    const int mat = blockIdx.y;
    const unsigned short* __restrict__ WThi = ms.WThi[mat];
    const unsigned short* __restrict__ WTlo = ms.WTlo[mat];
    const float* __restrict__ bias = ms.b[mat];
    float* __restrict__ C = ms.C[mat];
    const int t = threadIdx.x;
    const int w = t >> 6, lane = t & 63;
    const int q = lane >> 4, n = lane & 15;
    const int row0 = blockIdx.x * 128;

    int r0 = row0 + w * 32 + n;      if (r0 >= M) r0 = M - 1;
    int r1 = row0 + w * 32 + 16 + n; if (r1 >= M) r1 = M - 1;
    const size_t o0 = (size_t)r0 * D + q * 8;
    const size_t o1 = (size_t)r1 * D + q * 8;

    s16x8 ah[2][4], al[2][4];
#pragma unroll
    for (int kk = 0; kk < 4; ++kk) {
        ah[0][kk] = *(const s16x8*)(Ahi + o0 + kk * 32);
        ah[1][kk] = *(const s16x8*)(Ahi + o1 + kk * 32);
        al[0][kk] = *(const s16x8*)(Alo + o0 + kk * 32);
        al[1][kk] = *(const s16x8*)(Alo + o1 + kk * 32);
    }

    f32x4 acc[2][8];
#pragma unroll
    for (int tm = 0; tm < 2; ++tm)
#pragma unroll
        for (int tc = 0; tc < 8; ++tc) acc[tm][tc] = (f32x4){0.f, 0.f, 0.f, 0.f};

    // pass 1: W_hi (a_hi + a_lo)
#pragma unroll
    for (int i = 0; i < 8; ++i) {
        int flat = t * 8 + i * 2048;
        int r = flat >> 7, k = flat & 127;
        *(s16x8*)&sW[r * SWT_STRIDE + k] = *(const s16x8*)(WThi + flat);
    }
    __syncthreads();
#pragma unroll
    for (int kk = 0; kk < 4; ++kk) {
#pragma unroll
        for (int tc = 0; tc < 8; ++tc) {
            s16x8 bf = *(const s16x8*)&sW[(tc * 16 + n) * SWT_STRIDE + kk * 32 + q * 8];
            acc[0][tc] = __builtin_amdgcn_mfma_f32_16x16x32_bf16(ah[0][kk], bf, acc[0][tc], 0, 0, 0);
            acc[1][tc] = __builtin_amdgcn_mfma_f32_16x16x32_bf16(ah[1][kk], bf, acc[1][tc], 0, 0, 0);
            acc[0][tc] = __builtin_amdgcn_mfma_f32_16x16x32_bf16(al[0][kk], bf, acc[0][tc], 0, 0, 0);
            acc[1][tc] = __builtin_amdgcn_mfma_f32_16x16x32_bf16(al[1][kk], bf, acc[1][tc], 0, 0, 0);
        }
    }
    __syncthreads();

    // pass 2: W_lo (a_hi only)
#pragma unroll
    for (int i = 0; i < 8; ++i) {
        int flat = t * 8 + i * 2048;
        int r = flat >> 7, k = flat & 127;
        *(s16x8*)&sW[r * SWT_STRIDE + k] = *(const s16x8*)(WTlo + flat);
    }
    __syncthreads();
#pragma unroll
    for (int kk = 0; kk < 4; ++kk) {
#pragma unroll
        for (int tc = 0; tc < 8; ++tc) {
            s16x8 bf = *(const s16x8*)&sW[(tc * 16 + n) * SWT_STRIDE + kk * 32 + q * 8];
            acc[0][tc] = __builtin_amdgcn_mfma_f32_16x16x32_bf16(ah[0][kk], bf, acc[0][tc], 0, 0, 0);
            acc[1][tc] = __builtin_amdgcn_mfma_f32_16x16x32_bf16(ah[1][kk], bf, acc[1][tc], 0, 0, 0);
        }
    }

    float bs[8];
#pragma unroll
    for (int tc = 0; tc < 8; ++tc) bs[tc] = bias[tc * 16 + n];

#pragma unroll
    for (int tm = 0; tm < 2; ++tm)
#pragma unroll
        for (int r = 0; r < 4; ++r) {
            int row = row0 + w * 32 + tm * 16 + q * 4 + r;
            if (row >= M) continue;
#pragma unroll
            for (int tc = 0; tc < 8; ++tc)
                C[(size_t)row * D + tc * 16 + n] = acc[tm][tc][r] + bs[tc];
        }
}

// ---------- fused final MLP v2 (52224 B LDS => 3 blocks/CU; wave-private z staging)
__global__ __launch_bounds__(256, 3) void mfmm_final_kernel(
    const unsigned short* __restrict__ E,
    const unsigned short* __restrict__ WT1, const float* __restrict__ b1,
    const unsigned short* __restrict__ WT2, const float* __restrict__ b2,
    const float* __restrict__ f3w, const float* __restrict__ f3b,
    float* __restrict__ out, const int* __restrict__ perm)
{
    __shared__ unsigned short sW[128 * SWT_STRIDE];       // 34816 B: W1, then W2
    __shared__ unsigned short sZ[4 * 16 * SWT_STRIDE];    // 17408 B: per-wave z tile
    const int t = threadIdx.x;
    const int w = t >> 6, lane = t & 63;
    const int q = lane >> 4, n = lane & 15;
    const int row0 = blockIdx.x * 128;
    unsigned short* myZ = sZ + w * 16 * SWT_STRIDE;

    // prefetch this wave's 32 E rows (8 x b128 in flight across W1 staging)
    const unsigned short* a0p = E + (size_t)(row0 + w * 32 + n) * D + q * 8;
    s16x8 af[2][4];
#pragma unroll
    for (int kk = 0; kk < 4; ++kk) {
        af[0][kk] = *(const s16x8*)(a0p + kk * 32);
        af[1][kk] = *(const s16x8*)(a0p + 16 * D + kk * 32);
    }
    float bs1[8];
#pragma unroll
    for (int tc = 0; tc < 8; ++tc) bs1[tc] = b1[tc * 16 + n];

    // stage W1
#pragma unroll
    for (int i = 0; i < 8; ++i) {
        int flat = t * 8 + i * 2048;
        int r = flat >> 7, k = flat & 127;
        *(s16x8*)&sW[r * SWT_STRIDE + k] = *(const s16x8*)(WT1 + flat);
    }
    __syncthreads();

    // mm1: z1 = e @ W1
    f32x4 acc[2][8];
#pragma unroll
    for (int tm = 0; tm < 2; ++tm)
#pragma unroll
        for (int tc = 0; tc < 8; ++tc) acc[tm][tc] = (f32x4){0.f, 0.f, 0.f, 0.f};
#pragma unroll
    for (int kk = 0; kk < 4; ++kk) {
#pragma unroll
        for (int tc = 0; tc < 8; ++tc) {
            s16x8 bf = *(const s16x8*)&sW[(tc * 16 + n) * SWT_STRIDE + kk * 32 + q * 8];
            acc[0][tc] = __builtin_amdgcn_mfma_f32_16x16x32_bf16(af[0][kk], bf, acc[0][tc], 0, 0, 0);
            acc[1][tc] = __builtin_amdgcn_mfma_f32_16x16x32_bf16(af[1][kk], bf, acc[1][tc], 0, 0, 0);
        }
    }
    __syncthreads();  // all waves done reading W1

    // stage W2 into the same buffer
#pragma unroll
    for (int i = 0; i < 8; ++i) {
        int flat = t * 8 + i * 2048;
        int r = flat >> 7, k = flat & 127;
        *(s16x8*)&sW[r * SWT_STRIDE + k] = *(const s16x8*)(WT2 + flat);
    }
    __syncthreads();

    float bs2[8], f3v[8];
#pragma unroll
    for (int tc = 0; tc < 8; ++tc) {
        bs2[tc] = b2[tc * 16 + n];
        f3v[tc] = f3w[tc * 16 + n];
    }
    const float f3b0 = f3b[0];

    // per 16-row tile: wave-private z staging -> mm2 -> shfl-reduced f3 dot
#pragma unroll
    for (int m = 0; m < 2; ++m) {
#pragma unroll
        for (int tc = 0; tc < 8; ++tc)
#pragma unroll
            for (int r = 0; r < 4; ++r)
                myZ[(q * 4 + r) * SWT_STRIDE + tc * 16 + n] =
                    f2bf(silu_(acc[m][tc][r] + bs1[tc]));
        __asm__ volatile("s_waitcnt lgkmcnt(0)" ::: "memory");
        __builtin_amdgcn_sched_barrier(0);

        f32x4 a2[8];
#pragma unroll
        for (int tc = 0; tc < 8; ++tc) a2[tc] = (f32x4){0.f, 0.f, 0.f, 0.f};
#pragma unroll
        for (int kk = 0; kk < 4; ++kk) {
            s16x8 zf = *(const s16x8*)&myZ[n * SWT_STRIDE + kk * 32 + q * 8];
#pragma unroll
            for (int tc = 0; tc < 8; ++tc) {
                s16x8 bf = *(const s16x8*)&sW[(tc * 16 + n) * SWT_STRIDE + kk * 32 + q * 8];
                a2[tc] = __builtin_amdgcn_mfma_f32_16x16x32_bf16(zf, bf, a2[tc], 0, 0, 0);
            }
        }

#pragma unroll
        for (int r = 0; r < 4; ++r) {
            float p = 0.f;
#pragma unroll
            for (int tc = 0; tc < 8; ++tc)
                p = fmaf(silu_(a2[tc][r] + bs2[tc]), f3v[tc], p);
            p += __shfl_xor(p, 1);
            p += __shfl_xor(p, 2);
            p += __shfl_xor(p, 4);
            p += __shfl_xor(p, 8);
            if (n == 0) {
                int row = row0 + w * 32 + m * 16 + q * 4 + r;
                out[perm[row]] = sigm_(p + f3b0);
            }
        }
    }
}

// ---------- mfmm_te v3: t_e = e@Aw + Ab + Bh[psrc] + Ch[pdst] -> T, stat partials
//  Gather pipeline with NAMED SCALAR float4s only (rotating arrays get demoted
//  to scratch). 4 gathers issued before sync#2 (vmcnt(0) drain completes them);
//  steady state keeps a static 4-iteration load->use distance.
#define TE_GLD(BV, CV, I) \
    const float4 BV = *(const float4*)(Bh + (size_t)srs[I] * D + c4); \
    const float4 CV = *(const float4*)(Ch + (size_t)drs[I] * D + c4);

#define TE_CONS(BV, CV, I) { \
    int row_ = rg + (I) * 8; \
    ushort4 av_ = *(const ushort4*)&sW[row_ * SWT_STRIDE + c4]; \
    float t0_ = bf2f(av_.x) + BV.x + CV.x; \
    float t1_ = bf2f(av_.y) + BV.y + CV.y; \
    float t2_ = bf2f(av_.z) + BV.z + CV.z; \
    float t3_ = bf2f(av_.w) + BV.w + CV.w; \
    *(ushort4*)(T + (size_t)(row0 + row_) * D + c4) = \
        make_ushort4(f2bf(t0_), f2bf(t1_), f2bf(t2_), f2bf(t3_)); \
    s1[0] += t0_; s2[0] = fmaf(t0_, t0_, s2[0]); \
    s1[1] += t1_; s2[1] = fmaf(t1_, t1_, s2[1]); \
    s1[2] += t2_; s2[2] = fmaf(t2_, t2_, s2[2]); \
    s1[3] += t3_; s2[3] = fmaf(t3_, t3_, s2[3]); }

__global__ __launch_bounds__(256, 4) void mfmm_te_kernel(
    const unsigned short* __restrict__ A,   // e_bf (permuted order)
    const unsigned short* __restrict__ WT,
    const float* __restrict__ bias,
    const float* __restrict__ Bh, const float* __restrict__ Ch,
    const int* __restrict__ psrc, const int* __restrict__ pdst,
    unsigned short* __restrict__ T,
    float* __restrict__ P)
{
    __shared__ unsigned short sW[128 * SWT_STRIDE];
    const int t = threadIdx.x;
    const int w = t >> 6, lane = t & 63;
    const int q = lane >> 4, n = lane & 15;
    const int row0 = blockIdx.x * 128;

#pragma unroll
    for (int i = 0; i < 8; ++i) {
        int flat = t * 8 + i * 2048;
        int r = flat >> 7, k = flat & 127;
        *(s16x8*)&sW[r * SWT_STRIDE + k] = *(const s16x8*)(WT + flat);
    }
    __syncthreads();

    f32x4 acc[2][8];
#pragma unroll
    for (int tm = 0; tm < 2; ++tm)
#pragma unroll
        for (int tc = 0; tc < 8; ++tc) acc[tm][tc] = (f32x4){0.f, 0.f, 0.f, 0.f};

    const unsigned short* a0p = A + (size_t)(row0 + w * 32 + n) * D + q * 8;

#pragma unroll
    for (int kk = 0; kk < 128; kk += 32) {
        s16x8 af0 = *(const s16x8*)(a0p + kk);
        s16x8 af1 = *(const s16x8*)(a0p + 16 * D + kk);
#pragma unroll
        for (int tc = 0; tc < 8; ++tc) {
            s16x8 bf = *(const s16x8*)&sW[(tc * 16 + n) * SWT_STRIDE + kk + q * 8];
            acc[0][tc] = __builtin_amdgcn_mfma_f32_16x16x32_bf16(af0, bf, acc[0][tc], 0, 0, 0);
            acc[1][tc] = __builtin_amdgcn_mfma_f32_16x16x32_bf16(af1, bf, acc[1][tc], 0, 0, 0);
        }
    }

    float bs[8];
#pragma unroll
    for (int tc = 0; tc < 8; ++tc) bs[tc] = bias[tc * 16 + n];

    // index loads hoisted: latency drains under sync#1 + acc->LDS staging
    const int c4 = (t & 31) * 4;
    const int rg = t >> 5;
    int srs[16], drs[16];
#pragma unroll
    for (int i = 0; i < 16; ++i) {
        int eid = row0 + rg + i * 8;
        srs[i] = psrc[eid];
        drs[i] = pdst[eid];
    }

    __syncthreads();
#pragma unroll
    for (int tm = 0; tm < 2; ++tm)
#pragma unroll
        for (int tc = 0; tc < 8; ++tc)
#pragma unroll
            for (int r = 0; r < 4; ++r) {
                int row = w * 32 + tm * 16 + q * 4 + r;
                int col = tc * 16 + n;
                sW[row * SWT_STRIDE + col] = f2bf(acc[tm][tc][r] + bs[tc]);
            }

    // prefetch gathers 0..3 before the barrier (vmcnt(0) drain completes them)
    TE_GLD(bv0, cv0, 0)
    TE_GLD(bv1, cv1, 1)
    TE_GLD(bv2, cv2, 2)
    TE_GLD(bv3, cv3, 3)
    __syncthreads();

    float s1[4] = {0.f, 0.f, 0.f, 0.f}, s2[4] = {0.f, 0.f, 0.f, 0.f};
    // static 4-deep pipeline: issue load i+4, consume i
    TE_GLD(bv4, cv4, 4)    TE_CONS(bv0, cv0, 0)
    TE_GLD(bv5, cv5, 5)    TE_CONS(bv1, cv1, 1)
    TE_GLD(bv6, cv6, 6)    TE_CONS(bv2, cv2, 2)
    TE_GLD(bv7, cv7, 7)    TE_CONS(bv3, cv3, 3)
    TE_GLD(bv8, cv8, 8)    TE_CONS(bv4, cv4, 4)
    TE_GLD(bv9, cv9, 9)    TE_CONS(bv5, cv5, 5)
    TE_GLD(bv10, cv10, 10) TE_CONS(bv6, cv6, 6)
    TE_GLD(bv11, cv11, 11) TE_CONS(bv7, cv7, 7)
    TE_GLD(bv12, cv12, 12) TE_CONS(bv8, cv8, 8)
    TE_GLD(bv13, cv13, 13) TE_CONS(bv9, cv9, 9)
    TE_GLD(bv14, cv14, 14) TE_CONS(bv10, cv10, 10)
    TE_GLD(bv15, cv15, 15) TE_CONS(bv11, cv11, 11)
    TE_CONS(bv12, cv12, 12)
    TE_CONS(bv13, cv13, 13)
    TE_CONS(bv14, cv14, 14)
    TE_CONS(bv15, cv15, 15)

    __syncthreads();
    float* red = (float*)sW;
#pragma unroll
    for (int j = 0; j < 4; ++j) {
        red[rg * 128 + c4 + j] = s1[j];
        red[1024 + rg * 128 + c4 + j] = s2[j];
    }
    __syncthreads();
    if (t < 128) {
        float a = 0.f, b = 0.f;
#pragma unroll
        for (int g = 0; g < 8; ++g) { a += red[g * 128 + t]; b += red[1024 + g * 128 + t]; }
        P[(size_t)blockIdx.x * 256 + t] = a;
        P[(size_t)blockIdx.x * 256 + 128 + t] = b;
    }
}

// ---------- fused gather agg + apply_e v3: PAIR-UNROLLED (2 edges/iteration).
//  r5 lesson: deeper prefetch of ONE edge stream was neutral — the limit is
//  per-wave ILP (one ~80-cycle dependent sigmoid chain in flight per wave).
//  Two independent edge streams per iteration double trans/VALU ILP and loads
//  in flight, and halve loop overhead. Named scalars only (no arrays).
//  B-stream uses clamped indices: its agg contribution is masked by a 0/1
//  multiply; its duplicate store on odd degree recomputes identical bits
//  (its E value was loaded before any store to that row), so it's idempotent.
__global__ __launch_bounds__(256) void agg_apply_kernel(
    unsigned short* E, const unsigned short* __restrict__ T,
    const float* __restrict__ Vh, const float* __restrict__ stats,
    const int* __restrict__ rowptr, const int* __restrict__ pdst,
    const float* __restrict__ inv_cnt, float* __restrict__ Uh)
{
    int n = blockIdx.x * 4 + (threadIdx.x >> 6);
    if (n >= NN) return;
    int lane = threadIdx.x & 63;
    int c2 = lane * 2;
    float2 sc = *(const float2*)(stats + 2 * D + c2);
    float2 sh = *(const float2*)(stats + 3 * D + c2);
    int beg = rowptr[n], end = rowptr[n + 1];
    float a0 = 0.f, a1 = 0.f, b0 = 0.f, b1 = 0.f;

    if (beg < end) {
        const int m = end - 1;
        int jB0 = beg + 1 < m ? beg + 1 : m;
        int jA1 = beg + 2 < m ? beg + 2 : m;
        int jB1 = beg + 3 < m ? beg + 3 : m;
        int gA0 = pdst[beg], gB0 = pdst[jB0];
        int gA1 = pdst[jA1], gB1 = pdst[jB1];
        unsigned int epA0 = *(const unsigned int*)(E + (size_t)beg * D + c2);
        unsigned int tpA0 = *(const unsigned int*)(T + (size_t)beg * D + c2);
        unsigned int epB0 = *(const unsigned int*)(E + (size_t)jB0 * D + c2);
        unsigned int tpB0 = *(const unsigned int*)(T + (size_t)jB0 * D + c2);
        unsigned int epA1 = *(const unsigned int*)(E + (size_t)jA1 * D + c2);
        unsigned int tpA1 = *(const unsigned int*)(T + (size_t)jA1 * D + c2);
        unsigned int epB1 = *(const unsigned int*)(E + (size_t)jB1 * D + c2);
        unsigned int tpB1 = *(const unsigned int*)(T + (size_t)jB1 * D + c2);
        float2 vvA0 = *(const float2*)(Vh + (size_t)gA0 * D + c2);
        float2 vvB0 = *(const float2*)(Vh + (size_t)gB0 * D + c2);

        for (int j = beg; j < end; j += 2) {
            // prefetch pair k+2 (clamped; tail prefetches are discarded)
            int jA2 = j + 4 < m ? j + 4 : m;
            int jB2 = j + 5 < m ? j + 5 : m;
            int gA2 = pdst[jA2], gB2 = pdst[jB2];
            unsigned int epA2 = *(const unsigned int*)(E + (size_t)jA2 * D + c2);
            unsigned int tpA2 = *(const unsigned int*)(T + (size_t)jA2 * D + c2);
            unsigned int epB2 = *(const unsigned int*)(E + (size_t)jB2 * D + c2);
            unsigned int tpB2 = *(const unsigned int*)(T + (size_t)jB2 * D + c2);
            // issue Vh gathers for pair k+1 (indices resolved last iteration)
            float2 vvA1 = *(const float2*)(Vh + (size_t)gA1 * D + c2);
            float2 vvB1 = *(const float2*)(Vh + (size_t)gB1 * D + c2);

            // consume stream A (edge j, always valid)
            float eA0 = bf2f((unsigned short)(epA0 & 0xffff));
            float eA1 = bf2f((unsigned short)(epA0 >> 16));
            a0 = fmaf(sigm_(eA0), vvA0.x, a0);
            a1 = fmaf(sigm_(eA1), vvA0.y, a1);
            float tA0 = bf2f((unsigned short)(tpA0 & 0xffff));
            float tA1 = bf2f((unsigned short)(tpA0 >> 16));
            unsigned short oA0 = f2bf(eA0 + silu_(fmaf(tA0, sc.x, sh.x)));
            unsigned short oA1 = f2bf(eA1 + silu_(fmaf(tA1, sc.y, sh.y)));
            *(unsigned int*)(E + (size_t)j * D + c2) = ((unsigned int)oA1 << 16) | oA0;

            // consume stream B (edge j+1; agg masked if past end; store idempotent)
            float vb = (j + 1 < end) ? 1.f : 0.f;
            int jB = j + 1 < m ? j + 1 : m;
            float eB0 = bf2f((unsigned short)(epB0 & 0xffff));
            float eB1 = bf2f((unsigned short)(epB0 >> 16));
            b0 = fmaf(sigm_(eB0) * vb, vvB0.x, b0);
            b1 = fmaf(sigm_(eB1) * vb, vvB0.y, b1);
            float tB0 = bf2f((unsigned short)(tpB0 & 0xffff));
            float tB1 = bf2f((unsigned short)(tpB0 >> 16));
            unsigned short oB0 = f2bf(eB0 + silu_(fmaf(tB0, sc.x, sh.x)));
            unsigned short oB1 = f2bf(eB1 + silu_(fmaf(tB1, sc.y, sh.y)));
            *(unsigned int*)(E + (size_t)jB * D + c2) = ((unsigned int)oB1 << 16) | oB0;

            // rotate (named scalars)
            epA0 = epA1; tpA0 = tpA1; epB0 = epB1; tpB0 = tpB1;
            epA1 = epA2; tpA1 = tpA2; epB1 = epB2; tpB1 = tpB2;
            gA1 = gA2; gB1 = gB2;
            vvA0 = vvA1; vvB0 = vvB1;
        }
    }
    float ic = inv_cnt[n];
    size_t o = (size_t)n * D + c2;
    float2 u = *(const float2*)(Uh + o);
    u.x = fmaf(a0 + b0, ic, u.x);
    u.y = fmaf(a1 + b1, ic, u.y);
    *(float2*)(Uh + o) = u;
}

// ---------- stats: partial reduce (no atomics) + merged finalize
__global__ __launch_bounds__(256) void reduceE_kernel(
    const float* __restrict__ P, int nblk, float* __restrict__ P2)
{
    int t = threadIdx.x;
    float s = 0.f;
    for (int j = blockIdx.x; j < nblk; j += gridDim.x)
        s += P[(size_t)j * 256 + t];
    P2[blockIdx.x * 256 + t] = s;
}

__global__ void finalize2_kernel(const float* __restrict__ P, int nblk,
                                 const float* __restrict__ gamma,
                                 const float* __restrict__ beta,
                                 float inv_rows, float* __restrict__ stats)
{
    int c = threadIdx.x;  // 128
    float s1 = 0.f, s2 = 0.f;
    for (int j = 0; j < nblk; ++j) {
        s1 += P[j * 256 + c];
        s2 += P[j * 256 + 128 + c];
    }
    float m = s1 * inv_rows;
    float v = s2 * inv_rows - m * m;
    float rstd = rsqrtf(v + BN_EPS);
    float sc = gamma[c] * rstd;
    stats[2 * D + c] = sc;
    stats[3 * D + c] = beta[c] - m * sc;
}

// ---------- input projections (init_h emits hi/lo too)
__global__ __launch_bounds__(256) void init_h_kernel(
    const float* __restrict__ x, const float* __restrict__ hp_w,
    const float* __restrict__ hp_b, float* __restrict__ h,
    unsigned short* __restrict__ hhi, unsigned short* __restrict__ hlo)
{
    int idx = blockIdx.x * 256 + threadIdx.x;
    int n = idx >> 5, d = (idx & 31) * 4;
    if (n >= NN) return;
    float x0 = x[n * 2], x1 = x[n * 2 + 1];
    float4 w0 = *(const float4*)(hp_w + d);
    float4 w1 = *(const float4*)(hp_w + D + d);
    float4 b = *(const float4*)(hp_b + d);
    float4 o;
    o.x = silu_(fmaf(x0, w0.x, fmaf(x1, w1.x, b.x)));
    o.y = silu_(fmaf(x0, w0.y, fmaf(x1, w1.y, b.y)));
    o.z = silu_(fmaf(x0, w0.z, fmaf(x1, w1.z, b.z)));
    o.w = silu_(fmaf(x0, w0.w, fmaf(x1, w1.w, b.w)));
    *(float4*)(h + (size_t)n * D + d) = o;
    ushort4 hi = make_ushort4(f2bf(o.x), f2bf(o.y), f2bf(o.z), f2bf(o.w));
    ushort4 lo = make_ushort4(f2bf(o.x - bf2f(hi.x)), f2bf(o.y - bf2f(hi.y)),
                              f2bf(o.z - bf2f(hi.z)), f2bf(o.w - bf2f(hi.w)));
    *(ushort4*)(hhi + (size_t)n * D + d) = hi;
    *(ushort4*)(hlo + (size_t)n * D + d) = lo;
}

// init_e in PERMUTED order: row j <- edge eidx[j]
__global__ __launch_bounds__(256) void init_e_kernel(
    const float* __restrict__ ea, const int* __restrict__ eidx,
    const float* __restrict__ ep_w, const float* __restrict__ ep_b,
    unsigned short* __restrict__ e)
{
    int idx = blockIdx.x * 256 + threadIdx.x;
    int j = idx >> 5, d = (idx & 31) * 4;
    if (j >= NE) return;
    float a = ea[eidx[j]];
    float4 w = *(const float4*)(ep_w + d);
    float4 b = *(const float4*)(ep_b + d);
    ushort4 o;
    o.x = f2bf(silu_(fmaf(a, w.x, b.x)));
    o.y = f2bf(silu_(fmaf(a, w.y, b.y)));
    o.z = f2bf(silu_(fmaf(a, w.z, b.z)));
    o.w = f2bf(silu_(fmaf(a, w.w, b.w)));
    *(ushort4*)(e + (size_t)j * D + d) = o;
}

// ---------- CSR build
__global__ __launch_bounds__(256) void deg_kernel(const int* __restrict__ src, int* __restrict__ deg)
{
    int i = blockIdx.x * 256 + threadIdx.x;
    if (i < NE) atomicAdd(&deg[src[i]], 1);
}

__global__ __launch_bounds__(256) void scan_kernel(
    const int* __restrict__ deg, int* __restrict__ rowptr, float* __restrict__ inv_cnt)
{
    __shared__ int chunk[256];
    const int t = threadIdx.x;
    const int CH = (NN + 255) / 256;
    int s = 0;
    for (int i = 0; i < CH; ++i) {
        int idx = t * CH + i;
        if (idx < NN) s += deg[idx];
    }
    chunk[t] = s;
    __syncthreads();
    for (int offs = 1; offs < 256; offs <<= 1) {
        int v = (t >= offs) ? chunk[t - offs] : 0;
        __syncthreads();
        chunk[t] += v;
        __syncthreads();
    }
    int base = (t == 0) ? 0 : chunk[t - 1];
    for (int i = 0; i < CH; ++i) {
        int idx = t * CH + i;
        if (idx < NN) {
            rowptr[idx] = base;
            int d = deg[idx];
            inv_cnt[idx] = 1.0f / fmaxf((float)d, 1.0f);
            base += d;
        }
    }
    if (t == 255) rowptr[NN] = base;
}

__global__ __launch_bounds__(256) void fill_kernel(
    const int* __restrict__ src, const int* __restrict__ dst,
    const int* __restrict__ rowptr, int* __restrict__ cursor,
    int* __restrict__ eidx, int* __restrict__ psrc, int* __restrict__ pdst)
{
    int i = blockIdx.x * 256 + threadIdx.x;
    if (i >= NE) return;
    int s = src[i];
    int p = atomicAdd(&cursor[s], 1);
    int pos = rowptr[s] + p;
    eidx[pos] = i;
    psrc[pos] = s;
    pdst[pos] = dst[i];
}

// column stats partials of fp32 t_h (exactly 20 blocks; no atomics)
__global__ __launch_bounds__(256) void colstats_h_kernel(
    const float* __restrict__ Th, float* __restrict__ PH)
{
    __shared__ float red1[8][128], red2[8][128];
    int t = threadIdx.x;
    int c0 = (t & 31) * 4, half = t >> 5;
    int rbase = blockIdx.x * 1024;
    float s1[4] = {0, 0, 0, 0}, s2[4] = {0, 0, 0, 0};
    for (int i = 0; i < 128; ++i) {
        int r = rbase + half + 8 * i;
        if (r >= NN) break;
        float4 v = *(const float4*)(Th + (size_t)r * D + c0);
        s1[0] += v.x; s2[0] = fmaf(v.x, v.x, s2[0]);
        s1[1] += v.y; s2[1] = fmaf(v.y, v.y, s2[1]);
        s1[2] += v.z; s2[2] = fmaf(v.z, v.z, s2[2]);
        s1[3] += v.w; s2[3] = fmaf(v.w, v.w, s2[3]);
    }
#pragma unroll
    for (int j = 0; j < 4; ++j) { red1[half][c0 + j] = s1[j]; red2[half][c0 + j] = s2[j]; }
    __syncthreads();
    if (t < 128) {
        float a = 0.f, b = 0.f;
#pragma unroll
        for (int hh = 0; hh < 8; ++hh) { a += red1[hh][t]; b += red2[hh][t]; }
        PH[(size_t)blockIdx.x * 256 + t] = a;
        PH[(size_t)blockIdx.x * 256 + 128 + t] = b;
    }
}

// h += silu(t_h*sc+sh); also emit h_hi/h_lo for next layer's node matmul
__global__ __launch_bounds__(256) void apply_h_kernel(
    float* __restrict__ h, const float* __restrict__ Th, const float* __restrict__ stats,
    unsigned short* __restrict__ hhi, unsigned short* __restrict__ hlo)
{
    int idx = blockIdx.x * 256 + threadIdx.x;
    int r = idx >> 5, d = (idx & 31) * 4;
    if (r >= NN) return;
    float4 tv = *(const float4*)(Th + (size_t)r * D + d);
    float4 sc = *(const float4*)(stats + 2 * D + d);
    float4 sh = *(const float4*)(stats + 3 * D + d);
    float4 hv = *(const float4*)(h + (size_t)r * D + d);
    hv.x += silu_(fmaf(tv.x, sc.x, sh.x));
    hv.y += silu_(fmaf(tv.y, sc.y, sh.y));
    hv.z += silu_(fmaf(tv.z, sc.z, sh.z));
    hv.w += silu_(fmaf(tv.w, sc.w, sh.w));
    *(float4*)(h + (size_t)r * D + d) = hv;
    ushort4 hi = make_ushort4(f2bf(hv.x), f2bf(hv.y), f2bf(hv.z), f2bf(hv.w));
    ushort4 lo = make_ushort4(f2bf(hv.x - bf2f(hi.x)), f2bf(hv.y - bf2f(hi.y)),
                              f2bf(hv.z - bf2f(hi.z)), f2bf(hv.w - bf2f(hi.w)));
    *(ushort4*)(hhi + (size_t)r * D + d) = hi;
    *(ushort4*)(hlo + (size_t)r * D + d) = lo;
}

extern "C" void kernel_launch(void* const* d_in, const int* in_sizes, int n_in,
                              void* d_out, int out_size, void* d_ws, size_t ws_size,
                              hipStream_t stream)
{
    (void)in_sizes; (void)n_in; (void)out_size;
    const float* x = (const float*)d_in[0];
    const float* edge_attr = (const float*)d_in[1];
    const int* edge_index = (const int*)d_in[2];
    const int* src = edge_index;
    const int* dst = edge_index + NE;
    const float* hp_w = (const float*)d_in[3];
    const float* hp_b = (const float*)d_in[4];
    const float* ep_w = (const float*)d_in[5];
    const float* ep_b = (const float*)d_in[6];
    const float* Uw = (const float*)d_in[7];
    const float* Ub = (const float*)d_in[8];
    const float* Vw = (const float*)d_in[9];
    const float* Vb = (const float*)d_in[10];
    const float* Aw = (const float*)d_in[11];
    const float* Ab = (const float*)d_in[12];
    const float* Bw = (const float*)d_in[13];
    const float* Bb = (const float*)d_in[14];
    const float* Cw = (const float*)d_in[15];
    const float* Cb = (const float*)d_in[16];
    const float* h_gamma = (const float*)d_in[17];
    const float* h_beta = (const float*)d_in[18];
    const float* e_gamma = (const float*)d_in[19];
    const float* e_beta = (const float*)d_in[20];
    const float* f1w = (const float*)d_in[21];
    const float* f1b = (const float*)d_in[22];
    const float* f2w = (const float*)d_in[23];
    const float* f2b = (const float*)d_in[24];
    const float* f3w = (const float*)d_in[25];
    const float* f3b = (const float*)d_in[26];
    float* out = (float*)d_out;

    size_t off = 0;
    auto alloc = [&](size_t nbytes) {
        void* p = (char*)d_ws + off;
        off += ((nbytes + 255) / 256) * 256;
        return p;
    };
    unsigned short* e_bf = (unsigned short*)alloc((size_t)NE * D * 2);
    unsigned short* t_bf = (unsigned short*)alloc((size_t)NE * D * 2);
    float* h  = (float*)alloc((size_t)NN * D * 4);
    unsigned short* h_hi = (unsigned short*)alloc((size_t)NN * D * 2);
    unsigned short* h_lo = (unsigned short*)alloc((size_t)NN * D * 2);
    float* Uh = (float*)alloc((size_t)NN * D * 4);
    float* Vh = (float*)alloc((size_t)NN * D * 4);
    float* Bh = (float*)alloc((size_t)NN * D * 4);
    float* Ch = (float*)alloc((size_t)NN * D * 4);
    int* deg = (int*)alloc(NN * 4);
    int* rowptr = (int*)alloc((NN + 1) * 4);
    int* cursor = (int*)alloc(NN * 4);
    int* eidx = (int*)alloc((size_t)NE * 4);
    int* psrc = (int*)alloc((size_t)NE * 4);
    int* pdst = (int*)alloc((size_t)NE * 4);
    float* inv_cnt = (float*)alloc(NN * 4);
    float* statsH = (float*)alloc(4 * D * 4);
    float* statsE = (float*)alloc(4 * D * 4);
    float* Pstats = (float*)alloc((size_t)(NE / 128) * 256 * 4);
    float* PstatsH = (float*)alloc(20 * 256 * 4);
    float* PE2 = (float*)alloc(64 * 256 * 4);
    unsigned short* wtsNhi = (unsigned short*)alloc((size_t)12 * D * D * 2);
    unsigned short* wtsNlo = (unsigned short*)alloc((size_t)12 * D * D * 2);
    unsigned short* wtsE = (unsigned short*)alloc((size_t)5 * D * D * 2);  // A0,A1,A2,F1,F2

    if (off > ws_size) return;  // diagnostic guard

    const int nodeBlocks32 = (NN * 32 + 255) / 256;  // 2500
    const int edgeBlocks32 = (NE * 32) / 256;        // 40000
    const int nodeTiles = (NN + 127) / 128;          // 157
    const int edgeTiles = NE / 128;                  // 2500
    const int hBlocks = (NN + 1023) / 1024;          // 20

    // CSR build (needed before permuted init_e)
    hipMemsetAsync(deg, 0, NN * sizeof(int), stream);
    hipMemsetAsync(cursor, 0, NN * sizeof(int), stream);
    deg_kernel<<<NE / 256, 256, 0, stream>>>(src, deg);
    scan_kernel<<<1, 256, 0, stream>>>(deg, rowptr, inv_cnt);
    fill_kernel<<<NE / 256, 256, 0, stream>>>(src, dst, rowptr, cursor, eidx, psrc, pdst);

    init_h_kernel<<<nodeBlocks32, 256, 0, stream>>>(x, hp_w, hp_b, h, h_hi, h_lo);
    init_e_kernel<<<edgeBlocks32, 256, 0, stream>>>(edge_attr, eidx, ep_w, ep_b, e_bf);

    // all 17 weight conversions in one dispatch
    ConvJobs cj;
    const float* nodeW[4][3] = {{Uw, Uw + 16384, Uw + 32768},
                                {Vw, Vw + 16384, Vw + 32768},
                                {Bw, Bw + 16384, Bw + 32768},
                                {Cw, Cw + 16384, Cw + 32768}};
    for (int l = 0; l < LAYERS; ++l)
        for (int j = 0; j < 4; ++j) {
            int slot = l * 4 + j;
            cj.W[slot] = nodeW[j][l];
            cj.Hi[slot] = wtsNhi + (size_t)slot * D * D;
            cj.Lo[slot] = wtsNlo + (size_t)slot * D * D;
        }
    const float* edgeW[5] = {Aw, Aw + 16384, Aw + 32768, f1w, f2w};
    for (int j = 0; j < 5; ++j) {
        cj.W[12 + j] = edgeW[j];
        cj.Hi[12 + j] = wtsE + (size_t)j * D * D;
        cj.Lo[12 + j] = nullptr;
    }
    conv_all_kernel<<<dim3(64, 17), 256, 0, stream>>>(cj);

    for (int l = 0; l < LAYERS; ++l) {
        const size_t bl = (size_t)l * D;

        MatsB2 m4;
        for (int j = 0; j < 4; ++j) {
            size_t slot = (size_t)(l * 4 + j) * D * D;
            m4.WThi[j] = wtsNhi + slot;
            m4.WTlo[j] = wtsNlo + slot;
        }
        m4.b[0] = Ub + bl; m4.b[1] = Vb + bl; m4.b[2] = Bb + bl; m4.b[3] = Cb + bl;
        m4.C[0] = Uh; m4.C[1] = Vh; m4.C[2] = Bh; m4.C[3] = Ch;
        mfmm_node_kernel<<<dim3(nodeTiles, 4), 256, 0, stream>>>(h_hi, h_lo, NN, m4);

        // t_e matmul + gathers + stat partials
        mfmm_te_kernel<<<edgeTiles, 256, 0, stream>>>(
            e_bf, wtsE + (size_t)l * D * D, Ab + bl, Bh, Ch, psrc, pdst, t_bf, Pstats);

        // e stats
        reduceE_kernel<<<64, 256, 0, stream>>>(Pstats, edgeTiles, PE2);
        finalize2_kernel<<<1, D, 0, stream>>>(PE2, 64, e_gamma + bl, e_beta + bl,
                                              1.0f / NE, statsE);

        // fused aggregation + e-update (all layers; e_bf fully updated after layer 2)
        agg_apply_kernel<<<(NN + 3) / 4, 256, 0, stream>>>(
            e_bf, t_bf, Vh, statsE, rowptr, pdst, inv_cnt, Uh);

        // h update (partials -> merged finalize)
        colstats_h_kernel<<<hBlocks, 256, 0, stream>>>(Uh, PstatsH);
        finalize2_kernel<<<1, D, 0, stream>>>(PstatsH, hBlocks, h_gamma + bl, h_beta + bl,
                                              1.0f / NN, statsH);
        apply_h_kernel<<<nodeBlocks32, 256, 0, stream>>>(h, Uh, statsH, h_hi, h_lo);
    }

    // fused final MLP: f1 + f2 + f3 (e_bf already holds final e state)
    mfmm_final_kernel<<<edgeTiles, 256, 0, stream>>>(
        e_bf,
        wtsE + (size_t)3 * D * D, f1b,
        wtsE + (size_t)4 * D * D, f2b,
        f3w, f3b, out, eidx);
}

// Round 7
// 930.783 us; speedup vs baseline: 1.0015x; 1.0015x over previous
//
#include <hip/hip_runtime.h>

#define NN 20000
#define NE 320000
#define D 128
#define LAYERS 3
#define BN_EPS 1e-5f

typedef __attribute__((ext_vector_type(8))) short s16x8;
typedef __attribute__((ext_vector_type(4))) float f32x4;

// fast sigmoid: v_rcp_f32 instead of IEEE divide sequence (~1 ulp; outputs are
// bf16-rounded immediately so this is far below the accepted tolerance)
__device__ __forceinline__ float sigm_(float x) {
    return __builtin_amdgcn_rcpf(1.0f + __expf(-x));
}
__device__ __forceinline__ float silu_(float x) { return x * sigm_(x); }
__device__ __forceinline__ float bf2f(unsigned short u) {
    union { unsigned int u; float f; } v; v.u = ((unsigned int)u) << 16; return v.f;
}
__device__ __forceinline__ unsigned short f2bf(float f) {
    union { float f; unsigned int u; } v; v.f = f;
    return (unsigned short)((v.u + 0x7FFFu + ((v.u >> 16) & 1u)) >> 16);
}

#define SWT_STRIDE 136

// ---------- all weight conversions in one dispatch: blockIdx.y = job
struct ConvJobs {
    const float* W[17];
    unsigned short* Hi[17];
    unsigned short* Lo[17];  // nullptr => single bf16 convert
};
__global__ __launch_bounds__(256) void conv_all_kernel(ConvJobs jobs)
{
    int y = blockIdx.y;
    int idx = blockIdx.x * 256 + threadIdx.x;  // 16384
    int k = idx >> 7, n = idx & 127;
    float v = jobs.W[y][idx];
    unsigned short hi = f2bf(v);
    jobs.Hi[y][n * 128 + k] = hi;
    if (jobs.Lo[y]) jobs.Lo[y][n * 128 + k] = f2bf(v - bf2f(hi));
}

struct MatsB2 {
    const unsigned short* WThi[4];
    const unsigned short* WTlo[4];
    const float* b[4];
    float* C[4];
};

// ---------- split-precision MFMA node matmul
__global__ __launch_bounds__(256, 2) void mfmm_node_kernel(
    const unsigned short* __restrict__ Ahi, const unsigned short* __restrict__ Alo,
    int M, MatsB2 ms)
{
    __shared__ unsigned short sW[128 * SWT_STRIDE];
    const int mat = blockIdx.y;
    const unsigned short* __restrict__ WThi = ms.WThi[mat];
    const unsigned short* __restrict__ WTlo = ms.WTlo[mat];
    const float* __restrict__ bias = ms.b[mat];
    float* __restrict__ C = ms.C[mat];
    const int t = threadIdx.x;
    const int w = t >> 6, lane = t & 63;
    const int q = lane >> 4, n = lane & 15;
    const int row0 = blockIdx.x * 128;

    int r0 = row0 + w * 32 + n;      if (r0 >= M) r0 = M - 1;
    int r1 = row0 + w * 32 + 16 + n; if (r1 >= M) r1 = M - 1;
    const size_t o0 = (size_t)r0 * D + q * 8;
    const size_t o1 = (size_t)r1 * D + q * 8;

    s16x8 ah[2][4], al[2][4];
#pragma unroll
    for (int kk = 0; kk < 4; ++kk) {
        ah[0][kk] = *(const s16x8*)(Ahi + o0 + kk * 32);
        ah[1][kk] = *(const s16x8*)(Ahi + o1 + kk * 32);
        al[0][kk] = *(const s16x8*)(Alo + o0 + kk * 32);
        al[1][kk] = *(const s16x8*)(Alo + o1 + kk * 32);
    }

    f32x4 acc[2][8];
#pragma unroll
    for (int tm = 0; tm < 2; ++tm)
#pragma unroll
        for (int tc = 0; tc < 8; ++tc) acc[tm][tc] = (f32x4){0.f, 0.f, 0.f, 0.f};

    // pass 1: W_hi (a_hi + a_lo)
#pragma unroll
    for (int i = 0; i < 8; ++i) {
        int flat = t * 8 + i * 2048;
        int r = flat >> 7, k = flat & 127;
        *(s16x8*)&sW[r * SWT_STRIDE + k] = *(const s16x8*)(WThi + flat);
    }
    __syncthreads();
#pragma unroll
    for (int kk = 0; kk < 4; ++kk) {
#pragma unroll
        for (int tc = 0; tc < 8; ++tc) {
            s16x8 bf = *(const s16x8*)&sW[(tc * 16 + n) * SWT_STRIDE + kk * 32 + q * 8];
            acc[0][tc] = __builtin_amdgcn_mfma_f32_16x16x32_bf16(ah[0][kk], bf, acc[0][tc], 0, 0, 0);
            acc[1][tc] = __builtin_amdgcn_mfma_f32_16x16x32_bf16(ah[1][kk], bf, acc[1][tc], 0, 0, 0);
            acc[0][tc] = __builtin_amdgcn_mfma_f32_16x16x32_bf16(al[0][kk], bf, acc[0][tc], 0, 0, 0);
            acc[1][tc] = __builtin_amdgcn_mfma_f32_16x16x32_bf16(al[1][kk], bf, acc[1][tc], 0, 0, 0);
        }
    }
    __syncthreads();

    // pass 2: W_lo (a_hi only)
#pragma unroll
    for (int i = 0; i < 8; ++i) {
        int flat = t * 8 + i * 2048;
        int r = flat >> 7, k = flat & 127;
        *(s16x8*)&sW[r * SWT_STRIDE + k] = *(const s16x8*)(WTlo + flat);
    }
    __syncthreads();
#pragma unroll
    for (int kk = 0; kk < 4; ++kk) {
#pragma unroll
        for (int tc = 0; tc < 8; ++tc) {
            s16x8 bf = *(const s16x8*)&sW[(tc * 16 + n) * SWT_STRIDE + kk * 32 + q * 8];
            acc[0][tc] = __builtin_amdgcn_mfma_f32_16x16x32_bf16(ah[0][kk], bf, acc[0][tc], 0, 0, 0);
            acc[1][tc] = __builtin_amdgcn_mfma_f32_16x16x32_bf16(ah[1][kk], bf, acc[1][tc], 0, 0, 0);
        }
    }

    float bs[8];
#pragma unroll
    for (int tc = 0; tc < 8; ++tc) bs[tc] = bias[tc * 16 + n];

#pragma unroll
    for (int tm = 0; tm < 2; ++tm)
#pragma unroll
        for (int r = 0; r < 4; ++r) {
            int row = row0 + w * 32 + tm * 16 + q * 4 + r;
            if (row >= M) continue;
#pragma unroll
            for (int tc = 0; tc < 8; ++tc)
                C[(size_t)row * D + tc * 16 + n] = acc[tm][tc][r] + bs[tc];
        }
}

// ---------- fused final MLP v2 (52224 B LDS => 3 blocks/CU; wave-private z staging)
__global__ __launch_bounds__(256, 3) void mfmm_final_kernel(
    const unsigned short* __restrict__ E,
    const unsigned short* __restrict__ WT1, const float* __restrict__ b1,
    const unsigned short* __restrict__ WT2, const float* __restrict__ b2,
    const float* __restrict__ f3w, const float* __restrict__ f3b,
    float* __restrict__ out, const int* __restrict__ perm)
{
    __shared__ unsigned short sW[128 * SWT_STRIDE];       // 34816 B: W1, then W2
    __shared__ unsigned short sZ[4 * 16 * SWT_STRIDE];    // 17408 B: per-wave z tile
    const int t = threadIdx.x;
    const int w = t >> 6, lane = t & 63;
    const int q = lane >> 4, n = lane & 15;
    const int row0 = blockIdx.x * 128;
    unsigned short* myZ = sZ + w * 16 * SWT_STRIDE;

    // prefetch this wave's 32 E rows (8 x b128 in flight across W1 staging)
    const unsigned short* a0p = E + (size_t)(row0 + w * 32 + n) * D + q * 8;
    s16x8 af[2][4];
#pragma unroll
    for (int kk = 0; kk < 4; ++kk) {
        af[0][kk] = *(const s16x8*)(a0p + kk * 32);
        af[1][kk] = *(const s16x8*)(a0p + 16 * D + kk * 32);
    }
    float bs1[8];
#pragma unroll
    for (int tc = 0; tc < 8; ++tc) bs1[tc] = b1[tc * 16 + n];

    // stage W1
#pragma unroll
    for (int i = 0; i < 8; ++i) {
        int flat = t * 8 + i * 2048;
        int r = flat >> 7, k = flat & 127;
        *(s16x8*)&sW[r * SWT_STRIDE + k] = *(const s16x8*)(WT1 + flat);
    }
    __syncthreads();

    // mm1: z1 = e @ W1
    f32x4 acc[2][8];
#pragma unroll
    for (int tm = 0; tm < 2; ++tm)
#pragma unroll
        for (int tc = 0; tc < 8; ++tc) acc[tm][tc] = (f32x4){0.f, 0.f, 0.f, 0.f};
#pragma unroll
    for (int kk = 0; kk < 4; ++kk) {
#pragma unroll
        for (int tc = 0; tc < 8; ++tc) {
            s16x8 bf = *(const s16x8*)&sW[(tc * 16 + n) * SWT_STRIDE + kk * 32 + q * 8];
            acc[0][tc] = __builtin_amdgcn_mfma_f32_16x16x32_bf16(af[0][kk], bf, acc[0][tc], 0, 0, 0);
            acc[1][tc] = __builtin_amdgcn_mfma_f32_16x16x32_bf16(af[1][kk], bf, acc[1][tc], 0, 0, 0);
        }
    }
    __syncthreads();  // all waves done reading W1

    // stage W2 into the same buffer
#pragma unroll
    for (int i = 0; i < 8; ++i) {
        int flat = t * 8 + i * 2048;
        int r = flat >> 7, k = flat & 127;
        *(s16x8*)&sW[r * SWT_STRIDE + k] = *(const s16x8*)(WT2 + flat);
    }
    __syncthreads();

    float bs2[8], f3v[8];
#pragma unroll
    for (int tc = 0; tc < 8; ++tc) {
        bs2[tc] = b2[tc * 16 + n];
        f3v[tc] = f3w[tc * 16 + n];
    }
    const float f3b0 = f3b[0];

    // per 16-row tile: wave-private z staging -> mm2 -> shfl-reduced f3 dot
#pragma unroll
    for (int m = 0; m < 2; ++m) {
#pragma unroll
        for (int tc = 0; tc < 8; ++tc)
#pragma unroll
            for (int r = 0; r < 4; ++r)
                myZ[(q * 4 + r) * SWT_STRIDE + tc * 16 + n] =
                    f2bf(silu_(acc[m][tc][r] + bs1[tc]));
        __asm__ volatile("s_waitcnt lgkmcnt(0)" ::: "memory");
        __builtin_amdgcn_sched_barrier(0);

        f32x4 a2[8];
#pragma unroll
        for (int tc = 0; tc < 8; ++tc) a2[tc] = (f32x4){0.f, 0.f, 0.f, 0.f};
#pragma unroll
        for (int kk = 0; kk < 4; ++kk) {
            s16x8 zf = *(const s16x8*)&myZ[n * SWT_STRIDE + kk * 32 + q * 8];
#pragma unroll
            for (int tc = 0; tc < 8; ++tc) {
                s16x8 bf = *(const s16x8*)&sW[(tc * 16 + n) * SWT_STRIDE + kk * 32 + q * 8];
                a2[tc] = __builtin_amdgcn_mfma_f32_16x16x32_bf16(zf, bf, a2[tc], 0, 0, 0);
            }
        }

#pragma unroll
        for (int r = 0; r < 4; ++r) {
            float p = 0.f;
#pragma unroll
            for (int tc = 0; tc < 8; ++tc)
                p = fmaf(silu_(a2[tc][r] + bs2[tc]), f3v[tc], p);
            p += __shfl_xor(p, 1);
            p += __shfl_xor(p, 2);
            p += __shfl_xor(p, 4);
            p += __shfl_xor(p, 8);
            if (n == 0) {
                int row = row0 + w * 32 + m * 16 + q * 4 + r;
                out[perm[row]] = sigm_(p + f3b0);
            }
        }
    }
}

// ---------- mfmm_te v3: t_e = e@Aw + Ab + Bh[psrc] + Ch[pdst] -> T, stat partials
//  Gather pipeline with NAMED SCALAR float4s only (rotating arrays get demoted
//  to scratch). 4 gathers issued before sync#2 (vmcnt(0) drain completes them);
//  steady state keeps a static 4-iteration load->use distance.
#define TE_GLD(BV, CV, I) \
    const float4 BV = *(const float4*)(Bh + (size_t)srs[I] * D + c4); \
    const float4 CV = *(const float4*)(Ch + (size_t)drs[I] * D + c4);

#define TE_CONS(BV, CV, I) { \
    int row_ = rg + (I) * 8; \
    ushort4 av_ = *(const ushort4*)&sW[row_ * SWT_STRIDE + c4]; \
    float t0_ = bf2f(av_.x) + BV.x + CV.x; \
    float t1_ = bf2f(av_.y) + BV.y + CV.y; \
    float t2_ = bf2f(av_.z) + BV.z + CV.z; \
    float t3_ = bf2f(av_.w) + BV.w + CV.w; \
    *(ushort4*)(T + (size_t)(row0 + row_) * D + c4) = \
        make_ushort4(f2bf(t0_), f2bf(t1_), f2bf(t2_), f2bf(t3_)); \
    s1[0] += t0_; s2[0] = fmaf(t0_, t0_, s2[0]); \
    s1[1] += t1_; s2[1] = fmaf(t1_, t1_, s2[1]); \
    s1[2] += t2_; s2[2] = fmaf(t2_, t2_, s2[2]); \
    s1[3] += t3_; s2[3] = fmaf(t3_, t3_, s2[3]); }

__global__ __launch_bounds__(256, 4) void mfmm_te_kernel(
    const unsigned short* __restrict__ A,   // e_bf (permuted order)
    const unsigned short* __restrict__ WT,
    const float* __restrict__ bias,
    const float* __restrict__ Bh, const float* __restrict__ Ch,
    const int* __restrict__ psrc, const int* __restrict__ pdst,
    unsigned short* __restrict__ T,
    float* __restrict__ P)
{
    __shared__ unsigned short sW[128 * SWT_STRIDE];
    const int t = threadIdx.x;
    const int w = t >> 6, lane = t & 63;
    const int q = lane >> 4, n = lane & 15;
    const int row0 = blockIdx.x * 128;

#pragma unroll
    for (int i = 0; i < 8; ++i) {
        int flat = t * 8 + i * 2048;
        int r = flat >> 7, k = flat & 127;
        *(s16x8*)&sW[r * SWT_STRIDE + k] = *(const s16x8*)(WT + flat);
    }
    __syncthreads();

    f32x4 acc[2][8];
#pragma unroll
    for (int tm = 0; tm < 2; ++tm)
#pragma unroll
        for (int tc = 0; tc < 8; ++tc) acc[tm][tc] = (f32x4){0.f, 0.f, 0.f, 0.f};

    const unsigned short* a0p = A + (size_t)(row0 + w * 32 + n) * D + q * 8;

#pragma unroll
    for (int kk = 0; kk < 128; kk += 32) {
        s16x8 af0 = *(const s16x8*)(a0p + kk);
        s16x8 af1 = *(const s16x8*)(a0p + 16 * D + kk);
#pragma unroll
        for (int tc = 0; tc < 8; ++tc) {
            s16x8 bf = *(const s16x8*)&sW[(tc * 16 + n) * SWT_STRIDE + kk + q * 8];
            acc[0][tc] = __builtin_amdgcn_mfma_f32_16x16x32_bf16(af0, bf, acc[0][tc], 0, 0, 0);
            acc[1][tc] = __builtin_amdgcn_mfma_f32_16x16x32_bf16(af1, bf, acc[1][tc], 0, 0, 0);
        }
    }

    float bs[8];
#pragma unroll
    for (int tc = 0; tc < 8; ++tc) bs[tc] = bias[tc * 16 + n];

    // index loads hoisted: latency drains under sync#1 + acc->LDS staging
    const int c4 = (t & 31) * 4;
    const int rg = t >> 5;
    int srs[16], drs[16];
#pragma unroll
    for (int i = 0; i < 16; ++i) {
        int eid = row0 + rg + i * 8;
        srs[i] = psrc[eid];
        drs[i] = pdst[eid];
    }

    __syncthreads();
#pragma unroll
    for (int tm = 0; tm < 2; ++tm)
#pragma unroll
        for (int tc = 0; tc < 8; ++tc)
#pragma unroll
            for (int r = 0; r < 4; ++r) {
                int row = w * 32 + tm * 16 + q * 4 + r;
                int col = tc * 16 + n;
                sW[row * SWT_STRIDE + col] = f2bf(acc[tm][tc][r] + bs[tc]);
            }

    // prefetch gathers 0..3 before the barrier (vmcnt(0) drain completes them)
    TE_GLD(bv0, cv0, 0)
    TE_GLD(bv1, cv1, 1)
    TE_GLD(bv2, cv2, 2)
    TE_GLD(bv3, cv3, 3)
    __syncthreads();

    float s1[4] = {0.f, 0.f, 0.f, 0.f}, s2[4] = {0.f, 0.f, 0.f, 0.f};
    // static 4-deep pipeline: issue load i+4, consume i
    TE_GLD(bv4, cv4, 4)    TE_CONS(bv0, cv0, 0)
    TE_GLD(bv5, cv5, 5)    TE_CONS(bv1, cv1, 1)
    TE_GLD(bv6, cv6, 6)    TE_CONS(bv2, cv2, 2)
    TE_GLD(bv7, cv7, 7)    TE_CONS(bv3, cv3, 3)
    TE_GLD(bv8, cv8, 8)    TE_CONS(bv4, cv4, 4)
    TE_GLD(bv9, cv9, 9)    TE_CONS(bv5, cv5, 5)
    TE_GLD(bv10, cv10, 10) TE_CONS(bv6, cv6, 6)
    TE_GLD(bv11, cv11, 11) TE_CONS(bv7, cv7, 7)
    TE_GLD(bv12, cv12, 12) TE_CONS(bv8, cv8, 8)
    TE_GLD(bv13, cv13, 13) TE_CONS(bv9, cv9, 9)
    TE_GLD(bv14, cv14, 14) TE_CONS(bv10, cv10, 10)
    TE_GLD(bv15, cv15, 15) TE_CONS(bv11, cv11, 11)
    TE_CONS(bv12, cv12, 12)
    TE_CONS(bv13, cv13, 13)
    TE_CONS(bv14, cv14, 14)
    TE_CONS(bv15, cv15, 15)

    __syncthreads();
    float* red = (float*)sW;
#pragma unroll
    for (int j = 0; j < 4; ++j) {
        red[rg * 128 + c4 + j] = s1[j];
        red[1024 + rg * 128 + c4 + j] = s2[j];
    }
    __syncthreads();
    if (t < 128) {
        float a = 0.f, b = 0.f;
#pragma unroll
        for (int g = 0; g < 8; ++g) { a += red[g * 128 + t]; b += red[1024 + g * 128 + t]; }
        P[(size_t)blockIdx.x * 256 + t] = a;
        P[(size_t)blockIdx.x * 256 + 128 + t] = b;
    }
}

// ---------- fused gather agg + apply_e v4: WIDE-LANE remap.
//  r5/r6 lesson: pipelining/pair-ILP on 4B-granular loads was neutral — the
//  kernel was memory-INSTRUCTION bound (256 B per wave instruction). New
//  mapping: 8 channels/lane (b128), 16 lanes/edge, 4 CONTIGUOUS CSR rows per
//  wave per iteration => each E/T access is 1 KB contiguous per instruction,
//  ~6 memory instrs per 4 edges (was ~40), 4 independent sigmoid chains, and
//  serial depth deg/4. Tail handled by per-group exec masking; the clamped
//  prefetch address (js==j) is read-before-store in program order and only
//  occurs on the final iteration. Cross-group reduce: shfl_xor 16/32; lanes
//  0-15 apply the Uh row update.
__global__ __launch_bounds__(256) void agg_apply_kernel(
    unsigned short* E, const unsigned short* __restrict__ T,
    const float* __restrict__ Vh, const float* __restrict__ stats,
    const int* __restrict__ rowptr, const int* __restrict__ pdst,
    const float* __restrict__ inv_cnt, float* __restrict__ Uh)
{
    int n = blockIdx.x * 4 + (threadIdx.x >> 6);
    if (n >= NN) return;
    const int lane = threadIdx.x & 63;
    const int g = lane >> 4;          // edge group 0..3
    const int c8 = (lane & 15) * 8;   // channel base (8 ch/lane)
    float4 scA = *(const float4*)(stats + 2 * D + c8);
    float4 scB = *(const float4*)(stats + 2 * D + c8 + 4);
    float4 shA = *(const float4*)(stats + 3 * D + c8);
    float4 shB = *(const float4*)(stats + 3 * D + c8 + 4);
    int beg = rowptr[n], end = rowptr[n + 1];

    float a0 = 0.f, a1 = 0.f, a2 = 0.f, a3 = 0.f;
    float a4 = 0.f, a5 = 0.f, a6 = 0.f, a7 = 0.f;

    int j = beg + g;
    if (j < end) {
        int gi = pdst[j];
        s16x8 ep = *(const s16x8*)(E + (size_t)j * D + c8);
        s16x8 tp = *(const s16x8*)(T + (size_t)j * D + c8);
        while (j < end) {
            // prefetch next row for this group (clamped to own row on tail —
            // read precedes the store below in program order, and when js==j
            // the loop exits after this iteration so the value is unused)
            int j2 = j + 4;
            int js = j2 < end ? j2 : j;
            int gi2 = pdst[js];
            s16x8 ep2 = *(const s16x8*)(E + (size_t)js * D + c8);
            s16x8 tp2 = *(const s16x8*)(T + (size_t)js * D + c8);
            // Vh gather for current edge (8 floats)
            const float* vp = Vh + (size_t)gi * D + c8;
            float4 vA = *(const float4*)(vp);
            float4 vB = *(const float4*)(vp + 4);

            float e0 = bf2f((unsigned short)ep[0]);
            float e1 = bf2f((unsigned short)ep[1]);
            float e2 = bf2f((unsigned short)ep[2]);
            float e3 = bf2f((unsigned short)ep[3]);
            float e4 = bf2f((unsigned short)ep[4]);
            float e5 = bf2f((unsigned short)ep[5]);
            float e6 = bf2f((unsigned short)ep[6]);
            float e7 = bf2f((unsigned short)ep[7]);
            a0 = fmaf(sigm_(e0), vA.x, a0);
            a1 = fmaf(sigm_(e1), vA.y, a1);
            a2 = fmaf(sigm_(e2), vA.z, a2);
            a3 = fmaf(sigm_(e3), vA.w, a3);
            a4 = fmaf(sigm_(e4), vB.x, a4);
            a5 = fmaf(sigm_(e5), vB.y, a5);
            a6 = fmaf(sigm_(e6), vB.z, a6);
            a7 = fmaf(sigm_(e7), vB.w, a7);
            float t0 = bf2f((unsigned short)tp[0]);
            float t1 = bf2f((unsigned short)tp[1]);
            float t2 = bf2f((unsigned short)tp[2]);
            float t3 = bf2f((unsigned short)tp[3]);
            float t4 = bf2f((unsigned short)tp[4]);
            float t5 = bf2f((unsigned short)tp[5]);
            float t6 = bf2f((unsigned short)tp[6]);
            float t7 = bf2f((unsigned short)tp[7]);
            s16x8 o;
            o[0] = (short)f2bf(e0 + silu_(fmaf(t0, scA.x, shA.x)));
            o[1] = (short)f2bf(e1 + silu_(fmaf(t1, scA.y, shA.y)));
            o[2] = (short)f2bf(e2 + silu_(fmaf(t2, scA.z, shA.z)));
            o[3] = (short)f2bf(e3 + silu_(fmaf(t3, scA.w, shA.w)));
            o[4] = (short)f2bf(e4 + silu_(fmaf(t4, scB.x, shB.x)));
            o[5] = (short)f2bf(e5 + silu_(fmaf(t5, scB.y, shB.y)));
            o[6] = (short)f2bf(e6 + silu_(fmaf(t6, scB.z, shB.z)));
            o[7] = (short)f2bf(e7 + silu_(fmaf(t7, scB.w, shB.w)));
            *(s16x8*)(E + (size_t)j * D + c8) = o;

            j = j2;
            gi = gi2;
            ep = ep2;
            tp = tp2;
        }
    }
    // cross-group reduction: lanes {l, l+16, l+32, l+48} hold the same channels
    a0 += __shfl_xor(a0, 16); a0 += __shfl_xor(a0, 32);
    a1 += __shfl_xor(a1, 16); a1 += __shfl_xor(a1, 32);
    a2 += __shfl_xor(a2, 16); a2 += __shfl_xor(a2, 32);
    a3 += __shfl_xor(a3, 16); a3 += __shfl_xor(a3, 32);
    a4 += __shfl_xor(a4, 16); a4 += __shfl_xor(a4, 32);
    a5 += __shfl_xor(a5, 16); a5 += __shfl_xor(a5, 32);
    a6 += __shfl_xor(a6, 16); a6 += __shfl_xor(a6, 32);
    a7 += __shfl_xor(a7, 16); a7 += __shfl_xor(a7, 32);

    if (lane < 16) {
        float ic = inv_cnt[n];
        size_t o = (size_t)n * D + c8;
        float4 uA = *(const float4*)(Uh + o);
        float4 uB = *(const float4*)(Uh + o + 4);
        uA.x = fmaf(a0, ic, uA.x);
        uA.y = fmaf(a1, ic, uA.y);
        uA.z = fmaf(a2, ic, uA.z);
        uA.w = fmaf(a3, ic, uA.w);
        uB.x = fmaf(a4, ic, uB.x);
        uB.y = fmaf(a5, ic, uB.y);
        uB.z = fmaf(a6, ic, uB.z);
        uB.w = fmaf(a7, ic, uB.w);
        *(float4*)(Uh + o) = uA;
        *(float4*)(Uh + o + 4) = uB;
    }
}

// ---------- stats: partial reduce (no atomics) + merged finalize
__global__ __launch_bounds__(256) void reduceE_kernel(
    const float* __restrict__ P, int nblk, float* __restrict__ P2)
{
    int t = threadIdx.x;
    float s = 0.f;
    for (int j = blockIdx.x; j < nblk; j += gridDim.x)
        s += P[(size_t)j * 256 + t];
    P2[blockIdx.x * 256 + t] = s;
}

__global__ void finalize2_kernel(const float* __restrict__ P, int nblk,
                                 const float* __restrict__ gamma,
                                 const float* __restrict__ beta,
                                 float inv_rows, float* __restrict__ stats)
{
    int c = threadIdx.x;  // 128
    float s1 = 0.f, s2 = 0.f;
    for (int j = 0; j < nblk; ++j) {
        s1 += P[j * 256 + c];
        s2 += P[j * 256 + 128 + c];
    }
    float m = s1 * inv_rows;
    float v = s2 * inv_rows - m * m;
    float rstd = rsqrtf(v + BN_EPS);
    float sc = gamma[c] * rstd;
    stats[2 * D + c] = sc;
    stats[3 * D + c] = beta[c] - m * sc;
}

// ---------- input projections (init_h emits hi/lo too)
__global__ __launch_bounds__(256) void init_h_kernel(
    const float* __restrict__ x, const float* __restrict__ hp_w,
    const float* __restrict__ hp_b, float* __restrict__ h,
    unsigned short* __restrict__ hhi, unsigned short* __restrict__ hlo)
{
    int idx = blockIdx.x * 256 + threadIdx.x;
    int n = idx >> 5, d = (idx & 31) * 4;
    if (n >= NN) return;
    float x0 = x[n * 2], x1 = x[n * 2 + 1];
    float4 w0 = *(const float4*)(hp_w + d);
    float4 w1 = *(const float4*)(hp_w + D + d);
    float4 b = *(const float4*)(hp_b + d);
    float4 o;
    o.x = silu_(fmaf(x0, w0.x, fmaf(x1, w1.x, b.x)));
    o.y = silu_(fmaf(x0, w0.y, fmaf(x1, w1.y, b.y)));
    o.z = silu_(fmaf(x0, w0.z, fmaf(x1, w1.z, b.z)));
    o.w = silu_(fmaf(x0, w0.w, fmaf(x1, w1.w, b.w)));
    *(float4*)(h + (size_t)n * D + d) = o;
    ushort4 hi = make_ushort4(f2bf(o.x), f2bf(o.y), f2bf(o.z), f2bf(o.w));
    ushort4 lo = make_ushort4(f2bf(o.x - bf2f(hi.x)), f2bf(o.y - bf2f(hi.y)),
                              f2bf(o.z - bf2f(hi.z)), f2bf(o.w - bf2f(hi.w)));
    *(ushort4*)(hhi + (size_t)n * D + d) = hi;
    *(ushort4*)(hlo + (size_t)n * D + d) = lo;
}

// init_e in PERMUTED order: row j <- edge eidx[j]
__global__ __launch_bounds__(256) void init_e_kernel(
    const float* __restrict__ ea, const int* __restrict__ eidx,
    const float* __restrict__ ep_w, const float* __restrict__ ep_b,
    unsigned short* __restrict__ e)
{
    int idx = blockIdx.x * 256 + threadIdx.x;
    int j = idx >> 5, d = (idx & 31) * 4;
    if (j >= NE) return;
    float a = ea[eidx[j]];
    float4 w = *(const float4*)(ep_w + d);
    float4 b = *(const float4*)(ep_b + d);
    ushort4 o;
    o.x = f2bf(silu_(fmaf(a, w.x, b.x)));
    o.y = f2bf(silu_(fmaf(a, w.y, b.y)));
    o.z = f2bf(silu_(fmaf(a, w.z, b.z)));
    o.w = f2bf(silu_(fmaf(a, w.w, b.w)));
    *(ushort4*)(e + (size_t)j * D + d) = o;
}

// ---------- CSR build
__global__ __launch_bounds__(256) void deg_kernel(const int* __restrict__ src, int* __restrict__ deg)
{
    int i = blockIdx.x * 256 + threadIdx.x;
    if (i < NE) atomicAdd(&deg[src[i]], 1);
}

__global__ __launch_bounds__(256) void scan_kernel(
    const int* __restrict__ deg, int* __restrict__ rowptr, float* __restrict__ inv_cnt)
{
    __shared__ int chunk[256];
    const int t = threadIdx.x;
    const int CH = (NN + 255) / 256;
    int s = 0;
    for (int i = 0; i < CH; ++i) {
        int idx = t * CH + i;
        if (idx < NN) s += deg[idx];
    }
    chunk[t] = s;
    __syncthreads();
    for (int offs = 1; offs < 256; offs <<= 1) {
        int v = (t >= offs) ? chunk[t - offs] : 0;
        __syncthreads();
        chunk[t] += v;
        __syncthreads();
    }
    int base = (t == 0) ? 0 : chunk[t - 1];
    for (int i = 0; i < CH; ++i) {
        int idx = t * CH + i;
        if (idx < NN) {
            rowptr[idx] = base;
            int d = deg[idx];
            inv_cnt[idx] = 1.0f / fmaxf((float)d, 1.0f);
            base += d;
        }
    }
    if (t == 255) rowptr[NN] = base;
}

__global__ __launch_bounds__(256) void fill_kernel(
    const int* __restrict__ src, const int* __restrict__ dst,
    const int* __restrict__ rowptr, int* __restrict__ cursor,
    int* __restrict__ eidx, int* __restrict__ psrc, int* __restrict__ pdst)
{
    int i = blockIdx.x * 256 + threadIdx.x;
    if (i >= NE) return;
    int s = src[i];
    int p = atomicAdd(&cursor[s], 1);
    int pos = rowptr[s] + p;
    eidx[pos] = i;
    psrc[pos] = s;
    pdst[pos] = dst[i];
}

// column stats partials of fp32 t_h (exactly 20 blocks; no atomics)
__global__ __launch_bounds__(256) void colstats_h_kernel(
    const float* __restrict__ Th, float* __restrict__ PH)
{
    __shared__ float red1[8][128], red2[8][128];
    int t = threadIdx.x;
    int c0 = (t & 31) * 4, half = t >> 5;
    int rbase = blockIdx.x * 1024;
    float s1[4] = {0, 0, 0, 0}, s2[4] = {0, 0, 0, 0};
    for (int i = 0; i < 128; ++i) {
        int r = rbase + half + 8 * i;
        if (r >= NN) break;
        float4 v = *(const float4*)(Th + (size_t)r * D + c0);
        s1[0] += v.x; s2[0] = fmaf(v.x, v.x, s2[0]);
        s1[1] += v.y; s2[1] = fmaf(v.y, v.y, s2[1]);
        s1[2] += v.z; s2[2] = fmaf(v.z, v.z, s2[2]);
        s1[3] += v.w; s2[3] = fmaf(v.w, v.w, s2[3]);
    }
#pragma unroll
    for (int j = 0; j < 4; ++j) { red1[half][c0 + j] = s1[j]; red2[half][c0 + j] = s2[j]; }
    __syncthreads();
    if (t < 128) {
        float a = 0.f, b = 0.f;
#pragma unroll
        for (int hh = 0; hh < 8; ++hh) { a += red1[hh][t]; b += red2[hh][t]; }
        PH[(size_t)blockIdx.x * 256 + t] = a;
        PH[(size_t)blockIdx.x * 256 + 128 + t] = b;
    }
}

// h += silu(t_h*sc+sh); also emit h_hi/h_lo for next layer's node matmul
__global__ __launch_bounds__(256) void apply_h_kernel(
    float* __restrict__ h, const float* __restrict__ Th, const float* __restrict__ stats,
    unsigned short* __restrict__ hhi, unsigned short* __restrict__ hlo)
{
    int idx = blockIdx.x * 256 + threadIdx.x;
    int r = idx >> 5, d = (idx & 31) * 4;
    if (r >= NN) return;
    float4 tv = *(const float4*)(Th + (size_t)r * D + d);
    float4 sc = *(const float4*)(stats + 2 * D + d);
    float4 sh = *(const float4*)(stats + 3 * D + d);
    float4 hv = *(const float4*)(h + (size_t)r * D + d);
    hv.x += silu_(fmaf(tv.x, sc.x, sh.x));
    hv.y += silu_(fmaf(tv.y, sc.y, sh.y));
    hv.z += silu_(fmaf(tv.z, sc.z, sh.z));
    hv.w += silu_(fmaf(tv.w, sc.w, sh.w));
    *(float4*)(h + (size_t)r * D + d) = hv;
    ushort4 hi = make_ushort4(f2bf(hv.x), f2bf(hv.y), f2bf(hv.z), f2bf(hv.w));
    ushort4 lo = make_ushort4(f2bf(hv.x - bf2f(hi.x)), f2bf(hv.y - bf2f(hi.y)),
                              f2bf(hv.z - bf2f(hi.z)), f2bf(hv.w - bf2f(hi.w)));
    *(ushort4*)(hhi + (size_t)r * D + d) = hi;
    *(ushort4*)(hlo + (size_t)r * D + d) = lo;
}

extern "C" void kernel_launch(void* const* d_in, const int* in_sizes, int n_in,
                              void* d_out, int out_size, void* d_ws, size_t ws_size,
                              hipStream_t stream)
{
    (void)in_sizes; (void)n_in; (void)out_size;
    const float* x = (const float*)d_in[0];
    const float* edge_attr = (const float*)d_in[1];
    const int* edge_index = (const int*)d_in[2];
    const int* src = edge_index;
    const int* dst = edge_index + NE;
    const float* hp_w = (const float*)d_in[3];
    const float* hp_b = (const float*)d_in[4];
    const float* ep_w = (const float*)d_in[5];
    const float* ep_b = (const float*)d_in[6];
    const float* Uw = (const float*)d_in[7];
    const float* Ub = (const float*)d_in[8];
    const float* Vw = (const float*)d_in[9];
    const float* Vb = (const float*)d_in[10];
    const float* Aw = (const float*)d_in[11];
    const float* Ab = (const float*)d_in[12];
    const float* Bw = (const float*)d_in[13];
    const float* Bb = (const float*)d_in[14];
    const float* Cw = (const float*)d_in[15];
    const float* Cb = (const float*)d_in[16];
    const float* h_gamma = (const float*)d_in[17];
    const float* h_beta = (const float*)d_in[18];
    const float* e_gamma = (const float*)d_in[19];
    const float* e_beta = (const float*)d_in[20];
    const float* f1w = (const float*)d_in[21];
    const float* f1b = (const float*)d_in[22];
    const float* f2w = (const float*)d_in[23];
    const float* f2b = (const float*)d_in[24];
    const float* f3w = (const float*)d_in[25];
    const float* f3b = (const float*)d_in[26];
    float* out = (float*)d_out;

    size_t off = 0;
    auto alloc = [&](size_t nbytes) {
        void* p = (char*)d_ws + off;
        off += ((nbytes + 255) / 256) * 256;
        return p;
    };
    unsigned short* e_bf = (unsigned short*)alloc((size_t)NE * D * 2);
    unsigned short* t_bf = (unsigned short*)alloc((size_t)NE * D * 2);
    float* h  = (float*)alloc((size_t)NN * D * 4);
    unsigned short* h_hi = (unsigned short*)alloc((size_t)NN * D * 2);
    unsigned short* h_lo = (unsigned short*)alloc((size_t)NN * D * 2);
    float* Uh = (float*)alloc((size_t)NN * D * 4);
    float* Vh = (float*)alloc((size_t)NN * D * 4);
    float* Bh = (float*)alloc((size_t)NN * D * 4);
    float* Ch = (float*)alloc((size_t)NN * D * 4);
    int* deg = (int*)alloc(NN * 4);
    int* rowptr = (int*)alloc((NN + 1) * 4);
    int* cursor = (int*)alloc(NN * 4);
    int* eidx = (int*)alloc((size_t)NE * 4);
    int* psrc = (int*)alloc((size_t)NE * 4);
    int* pdst = (int*)alloc((size_t)NE * 4);
    float* inv_cnt = (float*)alloc(NN * 4);
    float* statsH = (float*)alloc(4 * D * 4);
    float* statsE = (float*)alloc(4 * D * 4);
    float* Pstats = (float*)alloc((size_t)(NE / 128) * 256 * 4);
    float* PstatsH = (float*)alloc(20 * 256 * 4);
    float* PE2 = (float*)alloc(64 * 256 * 4);
    unsigned short* wtsNhi = (unsigned short*)alloc((size_t)12 * D * D * 2);
    unsigned short* wtsNlo = (unsigned short*)alloc((size_t)12 * D * D * 2);
    unsigned short* wtsE = (unsigned short*)alloc((size_t)5 * D * D * 2);  // A0,A1,A2,F1,F2

    if (off > ws_size) return;  // diagnostic guard

    const int nodeBlocks32 = (NN * 32 + 255) / 256;  // 2500
    const int edgeBlocks32 = (NE * 32) / 256;        // 40000
    const int nodeTiles = (NN + 127) / 128;          // 157
    const int edgeTiles = NE / 128;                  // 2500
    const int hBlocks = (NN + 1023) / 1024;          // 20

    // CSR build (needed before permuted init_e)
    hipMemsetAsync(deg, 0, NN * sizeof(int), stream);
    hipMemsetAsync(cursor, 0, NN * sizeof(int), stream);
    deg_kernel<<<NE / 256, 256, 0, stream>>>(src, deg);
    scan_kernel<<<1, 256, 0, stream>>>(deg, rowptr, inv_cnt);
    fill_kernel<<<NE / 256, 256, 0, stream>>>(src, dst, rowptr, cursor, eidx, psrc, pdst);

    init_h_kernel<<<nodeBlocks32, 256, 0, stream>>>(x, hp_w, hp_b, h, h_hi, h_lo);
    init_e_kernel<<<edgeBlocks32, 256, 0, stream>>>(edge_attr, eidx, ep_w, ep_b, e_bf);

    // all 17 weight conversions in one dispatch
    ConvJobs cj;
    const float* nodeW[4][3] = {{Uw, Uw + 16384, Uw + 32768},
                                {Vw, Vw + 16384, Vw + 32768},
                                {Bw, Bw + 16384, Bw + 32768},
                                {Cw, Cw + 16384, Cw + 32768}};
    for (int l = 0; l < LAYERS; ++l)
        for (int j = 0; j < 4; ++j) {
            int slot = l * 4 + j;
            cj.W[slot] = nodeW[j][l];
            cj.Hi[slot] = wtsNhi + (size_t)slot * D * D;
            cj.Lo[slot] = wtsNlo + (size_t)slot * D * D;
        }
    const float* edgeW[5] = {Aw, Aw + 16384, Aw + 32768, f1w, f2w};
    for (int j = 0; j < 5; ++j) {
        cj.W[12 + j] = edgeW[j];
        cj.Hi[12 + j] = wtsE + (size_t)j * D * D;
        cj.Lo[12 + j] = nullptr;
    }
    conv_all_kernel<<<dim3(64, 17), 256, 0, stream>>>(cj);

    for (int l = 0; l < LAYERS; ++l) {
        const size_t bl = (size_t)l * D;

        MatsB2 m4;
        for (int j = 0; j < 4; ++j) {
            size_t slot = (size_t)(l * 4 + j) * D * D;
            m4.WThi[j] = wtsNhi + slot;
            m4.WTlo[j] = wtsNlo + slot;
        }
        m4.b[0] = Ub + bl; m4.b[1] = Vb + bl; m4.b[2] = Bb + bl; m4.b[3] = Cb + bl;
        m4.C[0] = Uh; m4.C[1] = Vh; m4.C[2] = Bh; m4.C[3] = Ch;
        mfmm_node_kernel<<<dim3(nodeTiles, 4), 256, 0, stream>>>(h_hi, h_lo, NN, m4);

        // t_e matmul + gathers + stat partials
        mfmm_te_kernel<<<edgeTiles, 256, 0, stream>>>(
            e_bf, wtsE + (size_t)l * D * D, Ab + bl, Bh, Ch, psrc, pdst, t_bf, Pstats);

        // e stats
        reduceE_kernel<<<64, 256, 0, stream>>>(Pstats, edgeTiles, PE2);
        finalize2_kernel<<<1, D, 0, stream>>>(PE2, 64, e_gamma + bl, e_beta + bl,
                                              1.0f / NE, statsE);

        // fused aggregation + e-update (all layers; e_bf fully updated after layer 2)
        agg_apply_kernel<<<(NN + 3) / 4, 256, 0, stream>>>(
            e_bf, t_bf, Vh, statsE, rowptr, pdst, inv_cnt, Uh);

        // h update (partials -> merged finalize)
        colstats_h_kernel<<<hBlocks, 256, 0, stream>>>(Uh, PstatsH);
        finalize2_kernel<<<1, D, 0, stream>>>(PstatsH, hBlocks, h_gamma + bl, h_beta + bl,
                                              1.0f / NN, statsH);
        apply_h_kernel<<<nodeBlocks32, 256, 0, stream>>>(h, Uh, statsH, h_hi, h_lo);
    }

    // fused final MLP: f1 + f2 + f3 (e_bf already holds final e state)
    mfmm_final_kernel<<<edgeTiles, 256, 0, stream>>>(
        e_bf,
        wtsE + (size_t)3 * D * D, f1b,
        wtsE + (size_t)4 * D * D, f2b,
        f3w, f3b, out, eidx);
}

// Round 8
// 871.501 us; speedup vs baseline: 1.0697x; 1.0680x over previous
//
#include <hip/hip_runtime.h>

#define NN 20000
#define NE 320000
#define D 128
#define LAYERS 3
#define BN_EPS 1e-5f

typedef __attribute__((ext_vector_type(8))) short s16x8;
typedef __attribute__((ext_vector_type(4))) float f32x4;

// fast sigmoid: v_rcp_f32 instead of IEEE divide sequence (~1 ulp; outputs are
// bf16-rounded immediately so this is far below the accepted tolerance)
__device__ __forceinline__ float sigm_(float x) {
    return __builtin_amdgcn_rcpf(1.0f + __expf(-x));
}
__device__ __forceinline__ float silu_(float x) { return x * sigm_(x); }
__device__ __forceinline__ float bf2f(unsigned short u) {
    union { unsigned int u; float f; } v; v.u = ((unsigned int)u) << 16; return v.f;
}
__device__ __forceinline__ unsigned short f2bf(float f) {
    union { float f; unsigned int u; } v; v.f = f;
    return (unsigned short)((v.u + 0x7FFFu + ((v.u >> 16) & 1u)) >> 16);
}

#define SWT_STRIDE 136

// ---------- all weight conversions in one dispatch: blockIdx.y = job
struct ConvJobs {
    const float* W[17];
    unsigned short* Hi[17];
    unsigned short* Lo[17];  // nullptr => single bf16 convert
};
__global__ __launch_bounds__(256) void conv_all_kernel(ConvJobs jobs)
{
    int y = blockIdx.y;
    int idx = blockIdx.x * 256 + threadIdx.x;  // 16384
    int k = idx >> 7, n = idx & 127;
    float v = jobs.W[y][idx];
    unsigned short hi = f2bf(v);
    jobs.Hi[y][n * 128 + k] = hi;
    if (jobs.Lo[y]) jobs.Lo[y][n * 128 + k] = f2bf(v - bf2f(hi));
}

struct MatsB2 {
    const unsigned short* WThi[4];
    const unsigned short* WTlo[4];
    const float* b[4];
    float* C[4];
};

// ---------- split-precision MFMA node matmul
__global__ __launch_bounds__(256, 2) void mfmm_node_kernel(
    const unsigned short* __restrict__ Ahi, const unsigned short* __restrict__ Alo,
    int M, MatsB2 ms)
{
    __shared__ unsigned short sW[128 * SWT_STRIDE];
    const int mat = blockIdx.y;
    const unsigned short* __restrict__ WThi = ms.WThi[mat];
    const unsigned short* __restrict__ WTlo = ms.WTlo[mat];
    const float* __restrict__ bias = ms.b[mat];
    float* __restrict__ C = ms.C[mat];
    const int t = threadIdx.x;
    const int w = t >> 6, lane = t & 63;
    const int q = lane >> 4, n = lane & 15;
    const int row0 = blockIdx.x * 128;

    int r0 = row0 + w * 32 + n;      if (r0 >= M) r0 = M - 1;
    int r1 = row0 + w * 32 + 16 + n; if (r1 >= M) r1 = M - 1;
    const size_t o0 = (size_t)r0 * D + q * 8;
    const size_t o1 = (size_t)r1 * D + q * 8;

    s16x8 ah[2][4], al[2][4];
#pragma unroll
    for (int kk = 0; kk < 4; ++kk) {
        ah[0][kk] = *(const s16x8*)(Ahi + o0 + kk * 32);
        ah[1][kk] = *(const s16x8*)(Ahi + o1 + kk * 32);
        al[0][kk] = *(const s16x8*)(Alo + o0 + kk * 32);
        al[1][kk] = *(const s16x8*)(Alo + o1 + kk * 32);
    }

    f32x4 acc[2][8];
#pragma unroll
    for (int tm = 0; tm < 2; ++tm)
#pragma unroll
        for (int tc = 0; tc < 8; ++tc) acc[tm][tc] = (f32x4){0.f, 0.f, 0.f, 0.f};

    // pass 1: W_hi (a_hi + a_lo)
#pragma unroll
    for (int i = 0; i < 8; ++i) {
        int flat = t * 8 + i * 2048;
        int r = flat >> 7, k = flat & 127;
        *(s16x8*)&sW[r * SWT_STRIDE + k] = *(const s16x8*)(WThi + flat);
    }
    __syncthreads();
#pragma unroll
    for (int kk = 0; kk < 4; ++kk) {
#pragma unroll
        for (int tc = 0; tc < 8; ++tc) {
            s16x8 bf = *(const s16x8*)&sW[(tc * 16 + n) * SWT_STRIDE + kk * 32 + q * 8];
            acc[0][tc] = __builtin_amdgcn_mfma_f32_16x16x32_bf16(ah[0][kk], bf, acc[0][tc], 0, 0, 0);
            acc[1][tc] = __builtin_amdgcn_mfma_f32_16x16x32_bf16(ah[1][kk], bf, acc[1][tc], 0, 0, 0);
            acc[0][tc] = __builtin_amdgcn_mfma_f32_16x16x32_bf16(al[0][kk], bf, acc[0][tc], 0, 0, 0);
            acc[1][tc] = __builtin_amdgcn_mfma_f32_16x16x32_bf16(al[1][kk], bf, acc[1][tc], 0, 0, 0);
        }
    }
    __syncthreads();

    // pass 2: W_lo (a_hi only)
#pragma unroll
    for (int i = 0; i < 8; ++i) {
        int flat = t * 8 + i * 2048;
        int r = flat >> 7, k = flat & 127;
        *(s16x8*)&sW[r * SWT_STRIDE + k] = *(const s16x8*)(WTlo + flat);
    }
    __syncthreads();
#pragma unroll
    for (int kk = 0; kk < 4; ++kk) {
#pragma unroll
        for (int tc = 0; tc < 8; ++tc) {
            s16x8 bf = *(const s16x8*)&sW[(tc * 16 + n) * SWT_STRIDE + kk * 32 + q * 8];
            acc[0][tc] = __builtin_amdgcn_mfma_f32_16x16x32_bf16(ah[0][kk], bf, acc[0][tc], 0, 0, 0);
            acc[1][tc] = __builtin_amdgcn_mfma_f32_16x16x32_bf16(ah[1][kk], bf, acc[1][tc], 0, 0, 0);
        }
    }

    float bs[8];
#pragma unroll
    for (int tc = 0; tc < 8; ++tc) bs[tc] = bias[tc * 16 + n];

#pragma unroll
    for (int tm = 0; tm < 2; ++tm)
#pragma unroll
        for (int r = 0; r < 4; ++r) {
            int row = row0 + w * 32 + tm * 16 + q * 4 + r;
            if (row >= M) continue;
#pragma unroll
            for (int tc = 0; tc < 8; ++tc)
                C[(size_t)row * D + tc * 16 + n] = acc[tm][tc][r] + bs[tc];
        }
}

// ---------- fused final MLP v3: applies layer-2 e-update on the fly.
//  Reads E_old + T + statsE, computes e' = e + silu(t*sc+sh) (same f2bf formula
//  as apply => bit-identical bf16), then f1+f2+f3. Saves agg(l2)'s T read +
//  E write (160 MB) at the cost of +82 MB T read here.
__global__ __launch_bounds__(256, 3) void mfmm_final_kernel(
    const unsigned short* __restrict__ E,
    const unsigned short* __restrict__ T,
    const float* __restrict__ stats,
    const unsigned short* __restrict__ WT1, const float* __restrict__ b1,
    const unsigned short* __restrict__ WT2, const float* __restrict__ b2,
    const float* __restrict__ f3w, const float* __restrict__ f3b,
    float* __restrict__ out, const int* __restrict__ perm)
{
    __shared__ unsigned short sW[128 * SWT_STRIDE];       // 34816 B: W1, then W2
    __shared__ unsigned short sZ[4 * 16 * SWT_STRIDE];    // 17408 B: per-wave z tile
    const int t = threadIdx.x;
    const int w = t >> 6, lane = t & 63;
    const int q = lane >> 4, n = lane & 15;
    const int row0 = blockIdx.x * 128;
    unsigned short* myZ = sZ + w * 16 * SWT_STRIDE;

    // prefetch E/T rows, apply e-update in registers -> af fragments
    const size_t base0 = (size_t)(row0 + w * 32 + n) * D + q * 8;
    s16x8 af[2][4];
#pragma unroll
    for (int kk = 0; kk < 4; ++kk) {
        s16x8 ev0 = *(const s16x8*)(E + base0 + kk * 32);
        s16x8 tv0 = *(const s16x8*)(T + base0 + kk * 32);
        s16x8 ev1 = *(const s16x8*)(E + base0 + 16 * D + kk * 32);
        s16x8 tv1 = *(const s16x8*)(T + base0 + 16 * D + kk * 32);
        int c = kk * 32 + q * 8;
        float4 scA = *(const float4*)(stats + 2 * D + c);
        float4 scB = *(const float4*)(stats + 2 * D + c + 4);
        float4 shA = *(const float4*)(stats + 3 * D + c);
        float4 shB = *(const float4*)(stats + 3 * D + c + 4);
        s16x8 r0, r1;
        r0[0] = (short)f2bf(bf2f((unsigned short)ev0[0]) + silu_(fmaf(bf2f((unsigned short)tv0[0]), scA.x, shA.x)));
        r0[1] = (short)f2bf(bf2f((unsigned short)ev0[1]) + silu_(fmaf(bf2f((unsigned short)tv0[1]), scA.y, shA.y)));
        r0[2] = (short)f2bf(bf2f((unsigned short)ev0[2]) + silu_(fmaf(bf2f((unsigned short)tv0[2]), scA.z, shA.z)));
        r0[3] = (short)f2bf(bf2f((unsigned short)ev0[3]) + silu_(fmaf(bf2f((unsigned short)tv0[3]), scA.w, shA.w)));
        r0[4] = (short)f2bf(bf2f((unsigned short)ev0[4]) + silu_(fmaf(bf2f((unsigned short)tv0[4]), scB.x, shB.x)));
        r0[5] = (short)f2bf(bf2f((unsigned short)ev0[5]) + silu_(fmaf(bf2f((unsigned short)tv0[5]), scB.y, shB.y)));
        r0[6] = (short)f2bf(bf2f((unsigned short)ev0[6]) + silu_(fmaf(bf2f((unsigned short)tv0[6]), scB.z, shB.z)));
        r0[7] = (short)f2bf(bf2f((unsigned short)ev0[7]) + silu_(fmaf(bf2f((unsigned short)tv0[7]), scB.w, shB.w)));
        r1[0] = (short)f2bf(bf2f((unsigned short)ev1[0]) + silu_(fmaf(bf2f((unsigned short)tv1[0]), scA.x, shA.x)));
        r1[1] = (short)f2bf(bf2f((unsigned short)ev1[1]) + silu_(fmaf(bf2f((unsigned short)tv1[1]), scA.y, shA.y)));
        r1[2] = (short)f2bf(bf2f((unsigned short)ev1[2]) + silu_(fmaf(bf2f((unsigned short)tv1[2]), scA.z, shA.z)));
        r1[3] = (short)f2bf(bf2f((unsigned short)ev1[3]) + silu_(fmaf(bf2f((unsigned short)tv1[3]), scA.w, shA.w)));
        r1[4] = (short)f2bf(bf2f((unsigned short)ev1[4]) + silu_(fmaf(bf2f((unsigned short)tv1[4]), scB.x, shB.x)));
        r1[5] = (short)f2bf(bf2f((unsigned short)ev1[5]) + silu_(fmaf(bf2f((unsigned short)tv1[5]), scB.y, shB.y)));
        r1[6] = (short)f2bf(bf2f((unsigned short)ev1[6]) + silu_(fmaf(bf2f((unsigned short)tv1[6]), scB.z, shB.z)));
        r1[7] = (short)f2bf(bf2f((unsigned short)ev1[7]) + silu_(fmaf(bf2f((unsigned short)tv1[7]), scB.w, shB.w)));
        af[0][kk] = r0;
        af[1][kk] = r1;
    }
    float bs1[8];
#pragma unroll
    for (int tc = 0; tc < 8; ++tc) bs1[tc] = b1[tc * 16 + n];

    // stage W1
#pragma unroll
    for (int i = 0; i < 8; ++i) {
        int flat = t * 8 + i * 2048;
        int r = flat >> 7, k = flat & 127;
        *(s16x8*)&sW[r * SWT_STRIDE + k] = *(const s16x8*)(WT1 + flat);
    }
    __syncthreads();

    // mm1: z1 = e' @ W1
    f32x4 acc[2][8];
#pragma unroll
    for (int tm = 0; tm < 2; ++tm)
#pragma unroll
        for (int tc = 0; tc < 8; ++tc) acc[tm][tc] = (f32x4){0.f, 0.f, 0.f, 0.f};
#pragma unroll
    for (int kk = 0; kk < 4; ++kk) {
#pragma unroll
        for (int tc = 0; tc < 8; ++tc) {
            s16x8 bf = *(const s16x8*)&sW[(tc * 16 + n) * SWT_STRIDE + kk * 32 + q * 8];
            acc[0][tc] = __builtin_amdgcn_mfma_f32_16x16x32_bf16(af[0][kk], bf, acc[0][tc], 0, 0, 0);
            acc[1][tc] = __builtin_amdgcn_mfma_f32_16x16x32_bf16(af[1][kk], bf, acc[1][tc], 0, 0, 0);
        }
    }
    __syncthreads();  // all waves done reading W1

    // stage W2 into the same buffer
#pragma unroll
    for (int i = 0; i < 8; ++i) {
        int flat = t * 8 + i * 2048;
        int r = flat >> 7, k = flat & 127;
        *(s16x8*)&sW[r * SWT_STRIDE + k] = *(const s16x8*)(WT2 + flat);
    }
    __syncthreads();

    float bs2[8], f3v[8];
#pragma unroll
    for (int tc = 0; tc < 8; ++tc) {
        bs2[tc] = b2[tc * 16 + n];
        f3v[tc] = f3w[tc * 16 + n];
    }
    const float f3b0 = f3b[0];

    // per 16-row tile: wave-private z staging -> mm2 -> shfl-reduced f3 dot
#pragma unroll
    for (int m = 0; m < 2; ++m) {
#pragma unroll
        for (int tc = 0; tc < 8; ++tc)
#pragma unroll
            for (int r = 0; r < 4; ++r)
                myZ[(q * 4 + r) * SWT_STRIDE + tc * 16 + n] =
                    f2bf(silu_(acc[m][tc][r] + bs1[tc]));
        __asm__ volatile("s_waitcnt lgkmcnt(0)" ::: "memory");
        __builtin_amdgcn_sched_barrier(0);

        f32x4 a2[8];
#pragma unroll
        for (int tc = 0; tc < 8; ++tc) a2[tc] = (f32x4){0.f, 0.f, 0.f, 0.f};
#pragma unroll
        for (int kk = 0; kk < 4; ++kk) {
            s16x8 zf = *(const s16x8*)&myZ[n * SWT_STRIDE + kk * 32 + q * 8];
#pragma unroll
            for (int tc = 0; tc < 8; ++tc) {
                s16x8 bf = *(const s16x8*)&sW[(tc * 16 + n) * SWT_STRIDE + kk * 32 + q * 8];
                a2[tc] = __builtin_amdgcn_mfma_f32_16x16x32_bf16(zf, bf, a2[tc], 0, 0, 0);
            }
        }

#pragma unroll
        for (int r = 0; r < 4; ++r) {
            float p = 0.f;
#pragma unroll
            for (int tc = 0; tc < 8; ++tc)
                p = fmaf(silu_(a2[tc][r] + bs2[tc]), f3v[tc], p);
            p += __shfl_xor(p, 1);
            p += __shfl_xor(p, 2);
            p += __shfl_xor(p, 4);
            p += __shfl_xor(p, 8);
            if (n == 0) {
                int row = row0 + w * 32 + m * 16 + q * 4 + r;
                out[perm[row]] = sigm_(p + f3b0);
            }
        }
    }
}

// ---------- mfmm_te v3: t_e = e@Aw + Ab + Bh[psrc] + Ch[pdst] -> T, stat partials
#define TE_GLD(BV, CV, I) \
    const float4 BV = *(const float4*)(Bh + (size_t)srs[I] * D + c4); \
    const float4 CV = *(const float4*)(Ch + (size_t)drs[I] * D + c4);

#define TE_CONS(BV, CV, I) { \
    int row_ = rg + (I) * 8; \
    ushort4 av_ = *(const ushort4*)&sW[row_ * SWT_STRIDE + c4]; \
    float t0_ = bf2f(av_.x) + BV.x + CV.x; \
    float t1_ = bf2f(av_.y) + BV.y + CV.y; \
    float t2_ = bf2f(av_.z) + BV.z + CV.z; \
    float t3_ = bf2f(av_.w) + BV.w + CV.w; \
    *(ushort4*)(T + (size_t)(row0 + row_) * D + c4) = \
        make_ushort4(f2bf(t0_), f2bf(t1_), f2bf(t2_), f2bf(t3_)); \
    s1[0] += t0_; s2[0] = fmaf(t0_, t0_, s2[0]); \
    s1[1] += t1_; s2[1] = fmaf(t1_, t1_, s2[1]); \
    s1[2] += t2_; s2[2] = fmaf(t2_, t2_, s2[2]); \
    s1[3] += t3_; s2[3] = fmaf(t3_, t3_, s2[3]); }

__global__ __launch_bounds__(256, 4) void mfmm_te_kernel(
    const unsigned short* __restrict__ A,   // e_bf (permuted order)
    const unsigned short* __restrict__ WT,
    const float* __restrict__ bias,
    const float* __restrict__ Bh, const float* __restrict__ Ch,
    const int* __restrict__ psrc, const int* __restrict__ pdst,
    unsigned short* __restrict__ T,
    float* __restrict__ P)
{
    __shared__ unsigned short sW[128 * SWT_STRIDE];
    const int t = threadIdx.x;
    const int w = t >> 6, lane = t & 63;
    const int q = lane >> 4, n = lane & 15;
    const int row0 = blockIdx.x * 128;

#pragma unroll
    for (int i = 0; i < 8; ++i) {
        int flat = t * 8 + i * 2048;
        int r = flat >> 7, k = flat & 127;
        *(s16x8*)&sW[r * SWT_STRIDE + k] = *(const s16x8*)(WT + flat);
    }
    __syncthreads();

    f32x4 acc[2][8];
#pragma unroll
    for (int tm = 0; tm < 2; ++tm)
#pragma unroll
        for (int tc = 0; tc < 8; ++tc) acc[tm][tc] = (f32x4){0.f, 0.f, 0.f, 0.f};

    const unsigned short* a0p = A + (size_t)(row0 + w * 32 + n) * D + q * 8;

#pragma unroll
    for (int kk = 0; kk < 128; kk += 32) {
        s16x8 af0 = *(const s16x8*)(a0p + kk);
        s16x8 af1 = *(const s16x8*)(a0p + 16 * D + kk);
#pragma unroll
        for (int tc = 0; tc < 8; ++tc) {
            s16x8 bf = *(const s16x8*)&sW[(tc * 16 + n) * SWT_STRIDE + kk + q * 8];
            acc[0][tc] = __builtin_amdgcn_mfma_f32_16x16x32_bf16(af0, bf, acc[0][tc], 0, 0, 0);
            acc[1][tc] = __builtin_amdgcn_mfma_f32_16x16x32_bf16(af1, bf, acc[1][tc], 0, 0, 0);
        }
    }

    float bs[8];
#pragma unroll
    for (int tc = 0; tc < 8; ++tc) bs[tc] = bias[tc * 16 + n];

    // index loads hoisted: latency drains under sync#1 + acc->LDS staging
    const int c4 = (t & 31) * 4;
    const int rg = t >> 5;
    int srs[16], drs[16];
#pragma unroll
    for (int i = 0; i < 16; ++i) {
        int eid = row0 + rg + i * 8;
        srs[i] = psrc[eid];
        drs[i] = pdst[eid];
    }

    __syncthreads();
#pragma unroll
    for (int tm = 0; tm < 2; ++tm)
#pragma unroll
        for (int tc = 0; tc < 8; ++tc)
#pragma unroll
            for (int r = 0; r < 4; ++r) {
                int row = w * 32 + tm * 16 + q * 4 + r;
                int col = tc * 16 + n;
                sW[row * SWT_STRIDE + col] = f2bf(acc[tm][tc][r] + bs[tc]);
            }

    // prefetch gathers 0..3 before the barrier (vmcnt(0) drain completes them)
    TE_GLD(bv0, cv0, 0)
    TE_GLD(bv1, cv1, 1)
    TE_GLD(bv2, cv2, 2)
    TE_GLD(bv3, cv3, 3)
    __syncthreads();

    float s1[4] = {0.f, 0.f, 0.f, 0.f}, s2[4] = {0.f, 0.f, 0.f, 0.f};
    // static 4-deep pipeline: issue load i+4, consume i
    TE_GLD(bv4, cv4, 4)    TE_CONS(bv0, cv0, 0)
    TE_GLD(bv5, cv5, 5)    TE_CONS(bv1, cv1, 1)
    TE_GLD(bv6, cv6, 6)    TE_CONS(bv2, cv2, 2)
    TE_GLD(bv7, cv7, 7)    TE_CONS(bv3, cv3, 3)
    TE_GLD(bv8, cv8, 8)    TE_CONS(bv4, cv4, 4)
    TE_GLD(bv9, cv9, 9)    TE_CONS(bv5, cv5, 5)
    TE_GLD(bv10, cv10, 10) TE_CONS(bv6, cv6, 6)
    TE_GLD(bv11, cv11, 11) TE_CONS(bv7, cv7, 7)
    TE_GLD(bv12, cv12, 12) TE_CONS(bv8, cv8, 8)
    TE_GLD(bv13, cv13, 13) TE_CONS(bv9, cv9, 9)
    TE_GLD(bv14, cv14, 14) TE_CONS(bv10, cv10, 10)
    TE_GLD(bv15, cv15, 15) TE_CONS(bv11, cv11, 11)
    TE_CONS(bv12, cv12, 12)
    TE_CONS(bv13, cv13, 13)
    TE_CONS(bv14, cv14, 14)
    TE_CONS(bv15, cv15, 15)

    __syncthreads();
    float* red = (float*)sW;
#pragma unroll
    for (int j = 0; j < 4; ++j) {
        red[rg * 128 + c4 + j] = s1[j];
        red[1024 + rg * 128 + c4 + j] = s2[j];
    }
    __syncthreads();
    if (t < 128) {
        float a = 0.f, b = 0.f;
#pragma unroll
        for (int g = 0; g < 8; ++g) { a += red[g * 128 + t]; b += red[1024 + g * 128 + t]; }
        P[(size_t)blockIdx.x * 256 + t] = a;
        P[(size_t)blockIdx.x * 256 + 128 + t] = b;
    }
}

// ---------- fused gather agg + apply_e (r6 pair version, best measured 62.0us).
//  APPLY=0 (last layer): gate+Uh only — no T reads, no E writes (the e-update
//  is applied on the fly inside mfmm_final). Named scalars only.
template <int APPLY>
__global__ __launch_bounds__(256) void agg_apply_kernel(
    unsigned short* E, const unsigned short* __restrict__ T,
    const float* __restrict__ Vh, const float* __restrict__ stats,
    const int* __restrict__ rowptr, const int* __restrict__ pdst,
    const float* __restrict__ inv_cnt, float* __restrict__ Uh)
{
    int n = blockIdx.x * 4 + (threadIdx.x >> 6);
    if (n >= NN) return;
    int lane = threadIdx.x & 63;
    int c2 = lane * 2;
    float2 sc = *(const float2*)(stats + 2 * D + c2);
    float2 sh = *(const float2*)(stats + 3 * D + c2);
    int beg = rowptr[n], end = rowptr[n + 1];
    float a0 = 0.f, a1 = 0.f, b0 = 0.f, b1 = 0.f;

    if (beg < end) {
        const int m = end - 1;
        int jB0 = beg + 1 < m ? beg + 1 : m;
        int jA1 = beg + 2 < m ? beg + 2 : m;
        int jB1 = beg + 3 < m ? beg + 3 : m;
        int gA0 = pdst[beg], gB0 = pdst[jB0];
        int gA1 = pdst[jA1], gB1 = pdst[jB1];
        unsigned int epA0 = *(const unsigned int*)(E + (size_t)beg * D + c2);
        unsigned int epB0 = *(const unsigned int*)(E + (size_t)jB0 * D + c2);
        unsigned int epA1 = *(const unsigned int*)(E + (size_t)jA1 * D + c2);
        unsigned int epB1 = *(const unsigned int*)(E + (size_t)jB1 * D + c2);
        unsigned int tpA0 = 0, tpB0 = 0, tpA1 = 0, tpB1 = 0;
        if (APPLY) {
            tpA0 = *(const unsigned int*)(T + (size_t)beg * D + c2);
            tpB0 = *(const unsigned int*)(T + (size_t)jB0 * D + c2);
            tpA1 = *(const unsigned int*)(T + (size_t)jA1 * D + c2);
            tpB1 = *(const unsigned int*)(T + (size_t)jB1 * D + c2);
        }
        float2 vvA0 = *(const float2*)(Vh + (size_t)gA0 * D + c2);
        float2 vvB0 = *(const float2*)(Vh + (size_t)gB0 * D + c2);

        for (int j = beg; j < end; j += 2) {
            // prefetch pair k+2 (clamped; tail prefetches are discarded)
            int jA2 = j + 4 < m ? j + 4 : m;
            int jB2 = j + 5 < m ? j + 5 : m;
            int gA2 = pdst[jA2], gB2 = pdst[jB2];
            unsigned int epA2 = *(const unsigned int*)(E + (size_t)jA2 * D + c2);
            unsigned int epB2 = *(const unsigned int*)(E + (size_t)jB2 * D + c2);
            unsigned int tpA2 = 0, tpB2 = 0;
            if (APPLY) {
                tpA2 = *(const unsigned int*)(T + (size_t)jA2 * D + c2);
                tpB2 = *(const unsigned int*)(T + (size_t)jB2 * D + c2);
            }
            // issue Vh gathers for pair k+1 (indices resolved last iteration)
            float2 vvA1 = *(const float2*)(Vh + (size_t)gA1 * D + c2);
            float2 vvB1 = *(const float2*)(Vh + (size_t)gB1 * D + c2);

            // consume stream A (edge j, always valid)
            float eA0 = bf2f((unsigned short)(epA0 & 0xffff));
            float eA1 = bf2f((unsigned short)(epA0 >> 16));
            a0 = fmaf(sigm_(eA0), vvA0.x, a0);
            a1 = fmaf(sigm_(eA1), vvA0.y, a1);
            if (APPLY) {
                float tA0 = bf2f((unsigned short)(tpA0 & 0xffff));
                float tA1 = bf2f((unsigned short)(tpA0 >> 16));
                unsigned short oA0 = f2bf(eA0 + silu_(fmaf(tA0, sc.x, sh.x)));
                unsigned short oA1 = f2bf(eA1 + silu_(fmaf(tA1, sc.y, sh.y)));
                *(unsigned int*)(E + (size_t)j * D + c2) = ((unsigned int)oA1 << 16) | oA0;
            }

            // consume stream B (edge j+1; agg masked if past end; store idempotent)
            float vb = (j + 1 < end) ? 1.f : 0.f;
            float eB0 = bf2f((unsigned short)(epB0 & 0xffff));
            float eB1 = bf2f((unsigned short)(epB0 >> 16));
            b0 = fmaf(sigm_(eB0) * vb, vvB0.x, b0);
            b1 = fmaf(sigm_(eB1) * vb, vvB0.y, b1);
            if (APPLY) {
                int jB = j + 1 < m ? j + 1 : m;
                float tB0 = bf2f((unsigned short)(tpB0 & 0xffff));
                float tB1 = bf2f((unsigned short)(tpB0 >> 16));
                unsigned short oB0 = f2bf(eB0 + silu_(fmaf(tB0, sc.x, sh.x)));
                unsigned short oB1 = f2bf(eB1 + silu_(fmaf(tB1, sc.y, sh.y)));
                *(unsigned int*)(E + (size_t)jB * D + c2) = ((unsigned int)oB1 << 16) | oB0;
            }

            // rotate (named scalars)
            epA0 = epA1; epB0 = epB1;
            epA1 = epA2; epB1 = epB2;
            if (APPLY) {
                tpA0 = tpA1; tpB0 = tpB1;
                tpA1 = tpA2; tpB1 = tpB2;
            }
            gA1 = gA2; gB1 = gB2;
            vvA0 = vvA1; vvB0 = vvB1;
        }
    }
    float ic = inv_cnt[n];
    size_t o = (size_t)n * D + c2;
    float2 u = *(const float2*)(Uh + o);
    u.x = fmaf(a0 + b0, ic, u.x);
    u.y = fmaf(a1 + b1, ic, u.y);
    *(float2*)(Uh + o) = u;
}

// ---------- E stats: 64-block partial reduce + last-block finalize (fused).
//  Standard decoupled pattern: partials -> threadfence -> device atomic ->
//  last block finalizes and self-resets the counter (graph-replay safe).
__global__ __launch_bounds__(256) void estats_kernel(
    const float* __restrict__ P, int nblk, float* __restrict__ P2,
    const float* __restrict__ gamma, const float* __restrict__ beta,
    float inv_rows, float* __restrict__ stats, int* __restrict__ counter)
{
    int t = threadIdx.x;
    float s = 0.f;
    for (int j = blockIdx.x; j < nblk; j += gridDim.x)
        s += P[(size_t)j * 256 + t];
    P2[blockIdx.x * 256 + t] = s;
    __threadfence();
    __shared__ int isLast;
    if (t == 0) isLast = (atomicAdd(counter, 1) == (int)gridDim.x - 1);
    __syncthreads();
    if (isLast) {
        if (t == 0) *counter = 0;
        __threadfence_block();
        if (t < 128) {
            float s1 = 0.f, s2 = 0.f;
            for (int j = 0; j < 64; ++j) {
                s1 += P2[j * 256 + t];
                s2 += P2[j * 256 + 128 + t];
            }
            float m = s1 * inv_rows;
            float v = s2 * inv_rows - m * m;
            float rstd = rsqrtf(v + BN_EPS);
            float scv = gamma[t] * rstd;
            stats[2 * D + t] = scv;
            stats[3 * D + t] = beta[t] - m * scv;
        }
    }
}

// ---------- H stats: 20-block column partials + last-block finalize (fused)
__global__ __launch_bounds__(256) void hstats_kernel(
    const float* __restrict__ Th, float* __restrict__ PH,
    const float* __restrict__ gamma, const float* __restrict__ beta,
    float inv_rows, float* __restrict__ stats, int* __restrict__ counter)
{
    __shared__ float red1[8][128], red2[8][128];
    int t = threadIdx.x;
    int c0 = (t & 31) * 4, half = t >> 5;
    int rbase = blockIdx.x * 1024;
    float s1[4] = {0, 0, 0, 0}, s2[4] = {0, 0, 0, 0};
    for (int i = 0; i < 128; ++i) {
        int r = rbase + half + 8 * i;
        if (r >= NN) break;
        float4 v = *(const float4*)(Th + (size_t)r * D + c0);
        s1[0] += v.x; s2[0] = fmaf(v.x, v.x, s2[0]);
        s1[1] += v.y; s2[1] = fmaf(v.y, v.y, s2[1]);
        s1[2] += v.z; s2[2] = fmaf(v.z, v.z, s2[2]);
        s1[3] += v.w; s2[3] = fmaf(v.w, v.w, s2[3]);
    }
#pragma unroll
    for (int j = 0; j < 4; ++j) { red1[half][c0 + j] = s1[j]; red2[half][c0 + j] = s2[j]; }
    __syncthreads();
    if (t < 128) {
        float a = 0.f, b = 0.f;
#pragma unroll
        for (int hh = 0; hh < 8; ++hh) { a += red1[hh][t]; b += red2[hh][t]; }
        PH[(size_t)blockIdx.x * 256 + t] = a;
        PH[(size_t)blockIdx.x * 256 + 128 + t] = b;
    }
    __threadfence();
    __shared__ int isLast;
    if (t == 0) isLast = (atomicAdd(counter, 1) == (int)gridDim.x - 1);
    __syncthreads();
    if (isLast) {
        if (t == 0) *counter = 0;
        __threadfence_block();
        if (t < 128) {
            float a = 0.f, b = 0.f;
            for (int j = 0; j < 20; ++j) {
                a += PH[(size_t)j * 256 + t];
                b += PH[(size_t)j * 256 + 128 + t];
            }
            float m = a * inv_rows;
            float v = b * inv_rows - m * m;
            float rstd = rsqrtf(v + BN_EPS);
            float scv = gamma[t] * rstd;
            stats[2 * D + t] = scv;
            stats[3 * D + t] = beta[t] - m * scv;
        }
    }
}

// ---------- input projections (init_h emits hi/lo too)
__global__ __launch_bounds__(256) void init_h_kernel(
    const float* __restrict__ x, const float* __restrict__ hp_w,
    const float* __restrict__ hp_b, float* __restrict__ h,
    unsigned short* __restrict__ hhi, unsigned short* __restrict__ hlo)
{
    int idx = blockIdx.x * 256 + threadIdx.x;
    int n = idx >> 5, d = (idx & 31) * 4;
    if (n >= NN) return;
    float x0 = x[n * 2], x1 = x[n * 2 + 1];
    float4 w0 = *(const float4*)(hp_w + d);
    float4 w1 = *(const float4*)(hp_w + D + d);
    float4 b = *(const float4*)(hp_b + d);
    float4 o;
    o.x = silu_(fmaf(x0, w0.x, fmaf(x1, w1.x, b.x)));
    o.y = silu_(fmaf(x0, w0.y, fmaf(x1, w1.y, b.y)));
    o.z = silu_(fmaf(x0, w0.z, fmaf(x1, w1.z, b.z)));
    o.w = silu_(fmaf(x0, w0.w, fmaf(x1, w1.w, b.w)));
    *(float4*)(h + (size_t)n * D + d) = o;
    ushort4 hi = make_ushort4(f2bf(o.x), f2bf(o.y), f2bf(o.z), f2bf(o.w));
    ushort4 lo = make_ushort4(f2bf(o.x - bf2f(hi.x)), f2bf(o.y - bf2f(hi.y)),
                              f2bf(o.z - bf2f(hi.z)), f2bf(o.w - bf2f(hi.w)));
    *(ushort4*)(hhi + (size_t)n * D + d) = hi;
    *(ushort4*)(hlo + (size_t)n * D + d) = lo;
}

// init_e in PERMUTED order: row j <- edge eidx[j]
__global__ __launch_bounds__(256) void init_e_kernel(
    const float* __restrict__ ea, const int* __restrict__ eidx,
    const float* __restrict__ ep_w, const float* __restrict__ ep_b,
    unsigned short* __restrict__ e)
{
    int idx = blockIdx.x * 256 + threadIdx.x;
    int j = idx >> 5, d = (idx & 31) * 4;
    if (j >= NE) return;
    float a = ea[eidx[j]];
    float4 w = *(const float4*)(ep_w + d);
    float4 b = *(const float4*)(ep_b + d);
    ushort4 o;
    o.x = f2bf(silu_(fmaf(a, w.x, b.x)));
    o.y = f2bf(silu_(fmaf(a, w.y, b.y)));
    o.z = f2bf(silu_(fmaf(a, w.z, b.z)));
    o.w = f2bf(silu_(fmaf(a, w.w, b.w)));
    *(ushort4*)(e + (size_t)j * D + d) = o;
}

// ---------- CSR build
__global__ __launch_bounds__(256) void deg_kernel(const int* __restrict__ src, int* __restrict__ deg)
{
    int i = blockIdx.x * 256 + threadIdx.x;
    if (i < NE) atomicAdd(&deg[src[i]], 1);
}

__global__ __launch_bounds__(256) void scan_kernel(
    const int* __restrict__ deg, int* __restrict__ rowptr, float* __restrict__ inv_cnt)
{
    __shared__ int chunk[256];
    const int t = threadIdx.x;
    const int CH = (NN + 255) / 256;
    int s = 0;
    for (int i = 0; i < CH; ++i) {
        int idx = t * CH + i;
        if (idx < NN) s += deg[idx];
    }
    chunk[t] = s;
    __syncthreads();
    for (int offs = 1; offs < 256; offs <<= 1) {
        int v = (t >= offs) ? chunk[t - offs] : 0;
        __syncthreads();
        chunk[t] += v;
        __syncthreads();
    }
    int base = (t == 0) ? 0 : chunk[t - 1];
    for (int i = 0; i < CH; ++i) {
        int idx = t * CH + i;
        if (idx < NN) {
            rowptr[idx] = base;
            int d = deg[idx];
            inv_cnt[idx] = 1.0f / fmaxf((float)d, 1.0f);
            base += d;
        }
    }
    if (t == 255) rowptr[NN] = base;
}

__global__ __launch_bounds__(256) void fill_kernel(
    const int* __restrict__ src, const int* __restrict__ dst,
    const int* __restrict__ rowptr, int* __restrict__ cursor,
    int* __restrict__ eidx, int* __restrict__ psrc, int* __restrict__ pdst)
{
    int i = blockIdx.x * 256 + threadIdx.x;
    if (i >= NE) return;
    int s = src[i];
    int p = atomicAdd(&cursor[s], 1);
    int pos = rowptr[s] + p;
    eidx[pos] = i;
    psrc[pos] = s;
    pdst[pos] = dst[i];
}

// h += silu(t_h*sc+sh); also emit h_hi/h_lo for next layer's node matmul
__global__ __launch_bounds__(256) void apply_h_kernel(
    float* __restrict__ h, const float* __restrict__ Th, const float* __restrict__ stats,
    unsigned short* __restrict__ hhi, unsigned short* __restrict__ hlo)
{
    int idx = blockIdx.x * 256 + threadIdx.x;
    int r = idx >> 5, d = (idx & 31) * 4;
    if (r >= NN) return;
    float4 tv = *(const float4*)(Th + (size_t)r * D + d);
    float4 sc = *(const float4*)(stats + 2 * D + d);
    float4 sh = *(const float4*)(stats + 3 * D + d);
    float4 hv = *(const float4*)(h + (size_t)r * D + d);
    hv.x += silu_(fmaf(tv.x, sc.x, sh.x));
    hv.y += silu_(fmaf(tv.y, sc.y, sh.y));
    hv.z += silu_(fmaf(tv.z, sc.z, sh.z));
    hv.w += silu_(fmaf(tv.w, sc.w, sh.w));
    *(float4*)(h + (size_t)r * D + d) = hv;
    ushort4 hi = make_ushort4(f2bf(hv.x), f2bf(hv.y), f2bf(hv.z), f2bf(hv.w));
    ushort4 lo = make_ushort4(f2bf(hv.x - bf2f(hi.x)), f2bf(hv.y - bf2f(hi.y)),
                              f2bf(hv.z - bf2f(hi.z)), f2bf(hv.w - bf2f(hi.w)));
    *(ushort4*)(hhi + (size_t)r * D + d) = hi;
    *(ushort4*)(hlo + (size_t)r * D + d) = lo;
}

extern "C" void kernel_launch(void* const* d_in, const int* in_sizes, int n_in,
                              void* d_out, int out_size, void* d_ws, size_t ws_size,
                              hipStream_t stream)
{
    (void)in_sizes; (void)n_in; (void)out_size;
    const float* x = (const float*)d_in[0];
    const float* edge_attr = (const float*)d_in[1];
    const int* edge_index = (const int*)d_in[2];
    const int* src = edge_index;
    const int* dst = edge_index + NE;
    const float* hp_w = (const float*)d_in[3];
    const float* hp_b = (const float*)d_in[4];
    const float* ep_w = (const float*)d_in[5];
    const float* ep_b = (const float*)d_in[6];
    const float* Uw = (const float*)d_in[7];
    const float* Ub = (const float*)d_in[8];
    const float* Vw = (const float*)d_in[9];
    const float* Vb = (const float*)d_in[10];
    const float* Aw = (const float*)d_in[11];
    const float* Ab = (const float*)d_in[12];
    const float* Bw = (const float*)d_in[13];
    const float* Bb = (const float*)d_in[14];
    const float* Cw = (const float*)d_in[15];
    const float* Cb = (const float*)d_in[16];
    const float* h_gamma = (const float*)d_in[17];
    const float* h_beta = (const float*)d_in[18];
    const float* e_gamma = (const float*)d_in[19];
    const float* e_beta = (const float*)d_in[20];
    const float* f1w = (const float*)d_in[21];
    const float* f1b = (const float*)d_in[22];
    const float* f2w = (const float*)d_in[23];
    const float* f2b = (const float*)d_in[24];
    const float* f3w = (const float*)d_in[25];
    const float* f3b = (const float*)d_in[26];
    float* out = (float*)d_out;

    size_t off = 0;
    auto alloc = [&](size_t nbytes) {
        void* p = (char*)d_ws + off;
        off += ((nbytes + 255) / 256) * 256;
        return p;
    };
    unsigned short* e_bf = (unsigned short*)alloc((size_t)NE * D * 2);
    unsigned short* t_bf = (unsigned short*)alloc((size_t)NE * D * 2);
    float* h  = (float*)alloc((size_t)NN * D * 4);
    unsigned short* h_hi = (unsigned short*)alloc((size_t)NN * D * 2);
    unsigned short* h_lo = (unsigned short*)alloc((size_t)NN * D * 2);
    float* Uh = (float*)alloc((size_t)NN * D * 4);
    float* Vh = (float*)alloc((size_t)NN * D * 4);
    float* Bh = (float*)alloc((size_t)NN * D * 4);
    float* Ch = (float*)alloc((size_t)NN * D * 4);
    int* deg = (int*)alloc(NN * 4);
    int* rowptr = (int*)alloc((NN + 1) * 4);
    int* cursor = (int*)alloc(NN * 4);
    int* eidx = (int*)alloc((size_t)NE * 4);
    int* psrc = (int*)alloc((size_t)NE * 4);
    int* pdst = (int*)alloc((size_t)NE * 4);
    float* inv_cnt = (float*)alloc(NN * 4);
    float* statsH = (float*)alloc(4 * D * 4);
    float* statsE = (float*)alloc(4 * D * 4);
    float* Pstats = (float*)alloc((size_t)(NE / 128) * 256 * 4);
    float* PstatsH = (float*)alloc(20 * 256 * 4);
    float* PE2 = (float*)alloc(64 * 256 * 4);
    unsigned short* wtsNhi = (unsigned short*)alloc((size_t)12 * D * D * 2);
    unsigned short* wtsNlo = (unsigned short*)alloc((size_t)12 * D * D * 2);
    unsigned short* wtsE = (unsigned short*)alloc((size_t)5 * D * D * 2);  // A0,A1,A2,F1,F2
    int* counters = (int*)alloc(2 * 4);

    if (off > ws_size) return;  // diagnostic guard

    const int nodeBlocks32 = (NN * 32 + 255) / 256;  // 2500
    const int edgeBlocks32 = (NE * 32) / 256;        // 40000
    const int nodeTiles = (NN + 127) / 128;          // 157
    const int edgeTiles = NE / 128;                  // 2500
    const int hBlocks = (NN + 1023) / 1024;          // 20

    // CSR build (needed before permuted init_e)
    hipMemsetAsync(deg, 0, NN * sizeof(int), stream);
    hipMemsetAsync(cursor, 0, NN * sizeof(int), stream);
    hipMemsetAsync(counters, 0, 2 * sizeof(int), stream);
    deg_kernel<<<NE / 256, 256, 0, stream>>>(src, deg);
    scan_kernel<<<1, 256, 0, stream>>>(deg, rowptr, inv_cnt);
    fill_kernel<<<NE / 256, 256, 0, stream>>>(src, dst, rowptr, cursor, eidx, psrc, pdst);

    init_h_kernel<<<nodeBlocks32, 256, 0, stream>>>(x, hp_w, hp_b, h, h_hi, h_lo);
    init_e_kernel<<<edgeBlocks32, 256, 0, stream>>>(edge_attr, eidx, ep_w, ep_b, e_bf);

    // all 17 weight conversions in one dispatch
    ConvJobs cj;
    const float* nodeW[4][3] = {{Uw, Uw + 16384, Uw + 32768},
                                {Vw, Vw + 16384, Vw + 32768},
                                {Bw, Bw + 16384, Bw + 32768},
                                {Cw, Cw + 16384, Cw + 32768}};
    for (int l = 0; l < LAYERS; ++l)
        for (int j = 0; j < 4; ++j) {
            int slot = l * 4 + j;
            cj.W[slot] = nodeW[j][l];
            cj.Hi[slot] = wtsNhi + (size_t)slot * D * D;
            cj.Lo[slot] = wtsNlo + (size_t)slot * D * D;
        }
    const float* edgeW[5] = {Aw, Aw + 16384, Aw + 32768, f1w, f2w};
    for (int j = 0; j < 5; ++j) {
        cj.W[12 + j] = edgeW[j];
        cj.Hi[12 + j] = wtsE + (size_t)j * D * D;
        cj.Lo[12 + j] = nullptr;
    }
    conv_all_kernel<<<dim3(64, 17), 256, 0, stream>>>(cj);

    for (int l = 0; l < LAYERS; ++l) {
        const size_t bl = (size_t)l * D;

        MatsB2 m4;
        for (int j = 0; j < 4; ++j) {
            size_t slot = (size_t)(l * 4 + j) * D * D;
            m4.WThi[j] = wtsNhi + slot;
            m4.WTlo[j] = wtsNlo + slot;
        }
        m4.b[0] = Ub + bl; m4.b[1] = Vb + bl; m4.b[2] = Bb + bl; m4.b[3] = Cb + bl;
        m4.C[0] = Uh; m4.C[1] = Vh; m4.C[2] = Bh; m4.C[3] = Ch;
        mfmm_node_kernel<<<dim3(nodeTiles, 4), 256, 0, stream>>>(h_hi, h_lo, NN, m4);

        // t_e matmul + gathers + stat partials
        mfmm_te_kernel<<<edgeTiles, 256, 0, stream>>>(
            e_bf, wtsE + (size_t)l * D * D, Ab + bl, Bh, Ch, psrc, pdst, t_bf, Pstats);

        // e stats: partial reduce + fused finalize (last-block pattern)
        estats_kernel<<<64, 256, 0, stream>>>(Pstats, edgeTiles, PE2,
                                              e_gamma + bl, e_beta + bl,
                                              1.0f / NE, statsE, counters + 0);

        // fused aggregation + e-update; last layer: agg only (final applies e)
        if (l < LAYERS - 1)
            agg_apply_kernel<1><<<(NN + 3) / 4, 256, 0, stream>>>(
                e_bf, t_bf, Vh, statsE, rowptr, pdst, inv_cnt, Uh);
        else
            agg_apply_kernel<0><<<(NN + 3) / 4, 256, 0, stream>>>(
                e_bf, t_bf, Vh, statsE, rowptr, pdst, inv_cnt, Uh);

        // h stats: column partials + fused finalize (last-block pattern)
        hstats_kernel<<<hBlocks, 256, 0, stream>>>(Uh, PstatsH,
                                                   h_gamma + bl, h_beta + bl,
                                                   1.0f / NN, statsH, counters + 1);
        apply_h_kernel<<<nodeBlocks32, 256, 0, stream>>>(h, Uh, statsH, h_hi, h_lo);
    }

    // fused final MLP: applies layer-2 e-update on the fly, then f1+f2+f3
    mfmm_final_kernel<<<edgeTiles, 256, 0, stream>>>(
        e_bf, t_bf, statsE,
        wtsE + (size_t)3 * D * D, f1b,
        wtsE + (size_t)4 * D * D, f2b,
        f3w, f3b, out, eidx);
}

// Round 9
// 784.304 us; speedup vs baseline: 1.1886x; 1.1112x over previous
//
#include <hip/hip_runtime.h>

#define NN 20000
#define NE 320000
#define D 128
#define LAYERS 3
#define BN_EPS 1e-5f

typedef __attribute__((ext_vector_type(8))) short s16x8;
typedef __attribute__((ext_vector_type(4))) float f32x4;

// fast sigmoid: v_rcp_f32 instead of IEEE divide sequence (~1 ulp; outputs are
// bf16-rounded immediately so this is far below the accepted tolerance)
__device__ __forceinline__ float sigm_(float x) {
    return __builtin_amdgcn_rcpf(1.0f + __expf(-x));
}
__device__ __forceinline__ float silu_(float x) { return x * sigm_(x); }
__device__ __forceinline__ float bf2f(unsigned short u) {
    union { unsigned int u; float f; } v; v.u = ((unsigned int)u) << 16; return v.f;
}
__device__ __forceinline__ unsigned short f2bf(float f) {
    union { float f; unsigned int u; } v; v.f = f;
    return (unsigned short)((v.u + 0x7FFFu + ((v.u >> 16) & 1u)) >> 16);
}

#define SWT_STRIDE 136

// ---------- all weight conversions in one dispatch: blockIdx.y = job
struct ConvJobs {
    const float* W[17];
    unsigned short* Hi[17];
    unsigned short* Lo[17];  // nullptr => single bf16 convert
};
__global__ __launch_bounds__(256) void conv_all_kernel(ConvJobs jobs)
{
    int y = blockIdx.y;
    int idx = blockIdx.x * 256 + threadIdx.x;  // 16384
    int k = idx >> 7, n = idx & 127;
    float v = jobs.W[y][idx];
    unsigned short hi = f2bf(v);
    jobs.Hi[y][n * 128 + k] = hi;
    if (jobs.Lo[y]) jobs.Lo[y][n * 128 + k] = f2bf(v - bf2f(hi));
}

struct MatsB2 {
    const unsigned short* WThi[4];
    const unsigned short* WTlo[4];
    const float* b[4];
    float* C[4];
};

// ---------- split-precision MFMA node matmul
__global__ __launch_bounds__(256, 2) void mfmm_node_kernel(
    const unsigned short* __restrict__ Ahi, const unsigned short* __restrict__ Alo,
    int M, MatsB2 ms)
{
    __shared__ unsigned short sW[128 * SWT_STRIDE];
    const int mat = blockIdx.y;
    const unsigned short* __restrict__ WThi = ms.WThi[mat];
    const unsigned short* __restrict__ WTlo = ms.WTlo[mat];
    const float* __restrict__ bias = ms.b[mat];
    float* __restrict__ C = ms.C[mat];
    const int t = threadIdx.x;
    const int w = t >> 6, lane = t & 63;
    const int q = lane >> 4, n = lane & 15;
    const int row0 = blockIdx.x * 128;

    int r0 = row0 + w * 32 + n;      if (r0 >= M) r0 = M - 1;
    int r1 = row0 + w * 32 + 16 + n; if (r1 >= M) r1 = M - 1;
    const size_t o0 = (size_t)r0 * D + q * 8;
    const size_t o1 = (size_t)r1 * D + q * 8;

    s16x8 ah[2][4], al[2][4];
#pragma unroll
    for (int kk = 0; kk < 4; ++kk) {
        ah[0][kk] = *(const s16x8*)(Ahi + o0 + kk * 32);
        ah[1][kk] = *(const s16x8*)(Ahi + o1 + kk * 32);
        al[0][kk] = *(const s16x8*)(Alo + o0 + kk * 32);
        al[1][kk] = *(const s16x8*)(Alo + o1 + kk * 32);
    }

    f32x4 acc[2][8];
#pragma unroll
    for (int tm = 0; tm < 2; ++tm)
#pragma unroll
        for (int tc = 0; tc < 8; ++tc) acc[tm][tc] = (f32x4){0.f, 0.f, 0.f, 0.f};

    // pass 1: W_hi (a_hi + a_lo)
#pragma unroll
    for (int i = 0; i < 8; ++i) {
        int flat = t * 8 + i * 2048;
        int r = flat >> 7, k = flat & 127;
        *(s16x8*)&sW[r * SWT_STRIDE + k] = *(const s16x8*)(WThi + flat);
    }
    __syncthreads();
#pragma unroll
    for (int kk = 0; kk < 4; ++kk) {
#pragma unroll
        for (int tc = 0; tc < 8; ++tc) {
            s16x8 bf = *(const s16x8*)&sW[(tc * 16 + n) * SWT_STRIDE + kk * 32 + q * 8];
            acc[0][tc] = __builtin_amdgcn_mfma_f32_16x16x32_bf16(ah[0][kk], bf, acc[0][tc], 0, 0, 0);
            acc[1][tc] = __builtin_amdgcn_mfma_f32_16x16x32_bf16(ah[1][kk], bf, acc[1][tc], 0, 0, 0);
            acc[0][tc] = __builtin_amdgcn_mfma_f32_16x16x32_bf16(al[0][kk], bf, acc[0][tc], 0, 0, 0);
            acc[1][tc] = __builtin_amdgcn_mfma_f32_16x16x32_bf16(al[1][kk], bf, acc[1][tc], 0, 0, 0);
        }
    }
    __syncthreads();

    // pass 2: W_lo (a_hi only)
#pragma unroll
    for (int i = 0; i < 8; ++i) {
        int flat = t * 8 + i * 2048;
        int r = flat >> 7, k = flat & 127;
        *(s16x8*)&sW[r * SWT_STRIDE + k] = *(const s16x8*)(WTlo + flat);
    }
    __syncthreads();
#pragma unroll
    for (int kk = 0; kk < 4; ++kk) {
#pragma unroll
        for (int tc = 0; tc < 8; ++tc) {
            s16x8 bf = *(const s16x8*)&sW[(tc * 16 + n) * SWT_STRIDE + kk * 32 + q * 8];
            acc[0][tc] = __builtin_amdgcn_mfma_f32_16x16x32_bf16(ah[0][kk], bf, acc[0][tc], 0, 0, 0);
            acc[1][tc] = __builtin_amdgcn_mfma_f32_16x16x32_bf16(ah[1][kk], bf, acc[1][tc], 0, 0, 0);
        }
    }

    float bs[8];
#pragma unroll
    for (int tc = 0; tc < 8; ++tc) bs[tc] = bias[tc * 16 + n];

#pragma unroll
    for (int tm = 0; tm < 2; ++tm)
#pragma unroll
        for (int r = 0; r < 4; ++r) {
            int row = row0 + w * 32 + tm * 16 + q * 4 + r;
            if (row >= M) continue;
#pragma unroll
            for (int tc = 0; tc < 8; ++tc)
                C[(size_t)row * D + tc * 16 + n] = acc[tm][tc][r] + bs[tc];
        }
}

// ---------- fused final MLP v3: applies layer-2 e-update on the fly.
//  Reads E_old + T + statsE, computes e' = e + silu(t*sc+sh), then f1+f2+f3.
__global__ __launch_bounds__(256, 3) void mfmm_final_kernel(
    const unsigned short* __restrict__ E,
    const unsigned short* __restrict__ T,
    const float* __restrict__ stats,
    const unsigned short* __restrict__ WT1, const float* __restrict__ b1,
    const unsigned short* __restrict__ WT2, const float* __restrict__ b2,
    const float* __restrict__ f3w, const float* __restrict__ f3b,
    float* __restrict__ out, const int* __restrict__ perm)
{
    __shared__ unsigned short sW[128 * SWT_STRIDE];       // 34816 B: W1, then W2
    __shared__ unsigned short sZ[4 * 16 * SWT_STRIDE];    // 17408 B: per-wave z tile
    const int t = threadIdx.x;
    const int w = t >> 6, lane = t & 63;
    const int q = lane >> 4, n = lane & 15;
    const int row0 = blockIdx.x * 128;
    unsigned short* myZ = sZ + w * 16 * SWT_STRIDE;

    // prefetch E/T rows, apply e-update in registers -> af fragments
    const size_t base0 = (size_t)(row0 + w * 32 + n) * D + q * 8;
    s16x8 af[2][4];
#pragma unroll
    for (int kk = 0; kk < 4; ++kk) {
        s16x8 ev0 = *(const s16x8*)(E + base0 + kk * 32);
        s16x8 tv0 = *(const s16x8*)(T + base0 + kk * 32);
        s16x8 ev1 = *(const s16x8*)(E + base0 + 16 * D + kk * 32);
        s16x8 tv1 = *(const s16x8*)(T + base0 + 16 * D + kk * 32);
        int c = kk * 32 + q * 8;
        float4 scA = *(const float4*)(stats + 2 * D + c);
        float4 scB = *(const float4*)(stats + 2 * D + c + 4);
        float4 shA = *(const float4*)(stats + 3 * D + c);
        float4 shB = *(const float4*)(stats + 3 * D + c + 4);
        s16x8 r0, r1;
        r0[0] = (short)f2bf(bf2f((unsigned short)ev0[0]) + silu_(fmaf(bf2f((unsigned short)tv0[0]), scA.x, shA.x)));
        r0[1] = (short)f2bf(bf2f((unsigned short)ev0[1]) + silu_(fmaf(bf2f((unsigned short)tv0[1]), scA.y, shA.y)));
        r0[2] = (short)f2bf(bf2f((unsigned short)ev0[2]) + silu_(fmaf(bf2f((unsigned short)tv0[2]), scA.z, shA.z)));
        r0[3] = (short)f2bf(bf2f((unsigned short)ev0[3]) + silu_(fmaf(bf2f((unsigned short)tv0[3]), scA.w, shA.w)));
        r0[4] = (short)f2bf(bf2f((unsigned short)ev0[4]) + silu_(fmaf(bf2f((unsigned short)tv0[4]), scB.x, shB.x)));
        r0[5] = (short)f2bf(bf2f((unsigned short)ev0[5]) + silu_(fmaf(bf2f((unsigned short)tv0[5]), scB.y, shB.y)));
        r0[6] = (short)f2bf(bf2f((unsigned short)ev0[6]) + silu_(fmaf(bf2f((unsigned short)tv0[6]), scB.z, shB.z)));
        r0[7] = (short)f2bf(bf2f((unsigned short)ev0[7]) + silu_(fmaf(bf2f((unsigned short)tv0[7]), scB.w, shB.w)));
        r1[0] = (short)f2bf(bf2f((unsigned short)ev1[0]) + silu_(fmaf(bf2f((unsigned short)tv1[0]), scA.x, shA.x)));
        r1[1] = (short)f2bf(bf2f((unsigned short)ev1[1]) + silu_(fmaf(bf2f((unsigned short)tv1[1]), scA.y, shA.y)));
        r1[2] = (short)f2bf(bf2f((unsigned short)ev1[2]) + silu_(fmaf(bf2f((unsigned short)tv1[2]), scA.z, shA.z)));
        r1[3] = (short)f2bf(bf2f((unsigned short)ev1[3]) + silu_(fmaf(bf2f((unsigned short)tv1[3]), scA.w, shA.w)));
        r1[4] = (short)f2bf(bf2f((unsigned short)ev1[4]) + silu_(fmaf(bf2f((unsigned short)tv1[4]), scB.x, shB.x)));
        r1[5] = (short)f2bf(bf2f((unsigned short)ev1[5]) + silu_(fmaf(bf2f((unsigned short)tv1[5]), scB.y, shB.y)));
        r1[6] = (short)f2bf(bf2f((unsigned short)ev1[6]) + silu_(fmaf(bf2f((unsigned short)tv1[6]), scB.z, shB.z)));
        r1[7] = (short)f2bf(bf2f((unsigned short)ev1[7]) + silu_(fmaf(bf2f((unsigned short)tv1[7]), scB.w, shB.w)));
        af[0][kk] = r0;
        af[1][kk] = r1;
    }
    float bs1[8];
#pragma unroll
    for (int tc = 0; tc < 8; ++tc) bs1[tc] = b1[tc * 16 + n];

    // stage W1
#pragma unroll
    for (int i = 0; i < 8; ++i) {
        int flat = t * 8 + i * 2048;
        int r = flat >> 7, k = flat & 127;
        *(s16x8*)&sW[r * SWT_STRIDE + k] = *(const s16x8*)(WT1 + flat);
    }
    __syncthreads();

    // mm1: z1 = e' @ W1
    f32x4 acc[2][8];
#pragma unroll
    for (int tm = 0; tm < 2; ++tm)
#pragma unroll
        for (int tc = 0; tc < 8; ++tc) acc[tm][tc] = (f32x4){0.f, 0.f, 0.f, 0.f};
#pragma unroll
    for (int kk = 0; kk < 4; ++kk) {
#pragma unroll
        for (int tc = 0; tc < 8; ++tc) {
            s16x8 bf = *(const s16x8*)&sW[(tc * 16 + n) * SWT_STRIDE + kk * 32 + q * 8];
            acc[0][tc] = __builtin_amdgcn_mfma_f32_16x16x32_bf16(af[0][kk], bf, acc[0][tc], 0, 0, 0);
            acc[1][tc] = __builtin_amdgcn_mfma_f32_16x16x32_bf16(af[1][kk], bf, acc[1][tc], 0, 0, 0);
        }
    }
    __syncthreads();  // all waves done reading W1

    // stage W2 into the same buffer
#pragma unroll
    for (int i = 0; i < 8; ++i) {
        int flat = t * 8 + i * 2048;
        int r = flat >> 7, k = flat & 127;
        *(s16x8*)&sW[r * SWT_STRIDE + k] = *(const s16x8*)(WT2 + flat);
    }
    __syncthreads();

    float bs2[8], f3v[8];
#pragma unroll
    for (int tc = 0; tc < 8; ++tc) {
        bs2[tc] = b2[tc * 16 + n];
        f3v[tc] = f3w[tc * 16 + n];
    }
    const float f3b0 = f3b[0];

    // per 16-row tile: wave-private z staging -> mm2 -> shfl-reduced f3 dot
#pragma unroll
    for (int m = 0; m < 2; ++m) {
#pragma unroll
        for (int tc = 0; tc < 8; ++tc)
#pragma unroll
            for (int r = 0; r < 4; ++r)
                myZ[(q * 4 + r) * SWT_STRIDE + tc * 16 + n] =
                    f2bf(silu_(acc[m][tc][r] + bs1[tc]));
        __asm__ volatile("s_waitcnt lgkmcnt(0)" ::: "memory");
        __builtin_amdgcn_sched_barrier(0);

        f32x4 a2[8];
#pragma unroll
        for (int tc = 0; tc < 8; ++tc) a2[tc] = (f32x4){0.f, 0.f, 0.f, 0.f};
#pragma unroll
        for (int kk = 0; kk < 4; ++kk) {
            s16x8 zf = *(const s16x8*)&myZ[n * SWT_STRIDE + kk * 32 + q * 8];
#pragma unroll
            for (int tc = 0; tc < 8; ++tc) {
                s16x8 bf = *(const s16x8*)&sW[(tc * 16 + n) * SWT_STRIDE + kk * 32 + q * 8];
                a2[tc] = __builtin_amdgcn_mfma_f32_16x16x32_bf16(zf, bf, a2[tc], 0, 0, 0);
            }
        }

#pragma unroll
        for (int r = 0; r < 4; ++r) {
            float p = 0.f;
#pragma unroll
            for (int tc = 0; tc < 8; ++tc)
                p = fmaf(silu_(a2[tc][r] + bs2[tc]), f3v[tc], p);
            p += __shfl_xor(p, 1);
            p += __shfl_xor(p, 2);
            p += __shfl_xor(p, 4);
            p += __shfl_xor(p, 8);
            if (n == 0) {
                int row = row0 + w * 32 + m * 16 + q * 4 + r;
                out[perm[row]] = sigm_(p + f3b0);
            }
        }
    }
}

// ---------- mfmm_te v3: t_e = e@Aw + Ab + Bh[psrc] + Ch[pdst] -> T, stat partials
#define TE_GLD(BV, CV, I) \
    const float4 BV = *(const float4*)(Bh + (size_t)srs[I] * D + c4); \
    const float4 CV = *(const float4*)(Ch + (size_t)drs[I] * D + c4);

#define TE_CONS(BV, CV, I) { \
    int row_ = rg + (I) * 8; \
    ushort4 av_ = *(const ushort4*)&sW[row_ * SWT_STRIDE + c4]; \
    float t0_ = bf2f(av_.x) + BV.x + CV.x; \
    float t1_ = bf2f(av_.y) + BV.y + CV.y; \
    float t2_ = bf2f(av_.z) + BV.z + CV.z; \
    float t3_ = bf2f(av_.w) + BV.w + CV.w; \
    *(ushort4*)(T + (size_t)(row0 + row_) * D + c4) = \
        make_ushort4(f2bf(t0_), f2bf(t1_), f2bf(t2_), f2bf(t3_)); \
    s1[0] += t0_; s2[0] = fmaf(t0_, t0_, s2[0]); \
    s1[1] += t1_; s2[1] = fmaf(t1_, t1_, s2[1]); \
    s1[2] += t2_; s2[2] = fmaf(t2_, t2_, s2[2]); \
    s1[3] += t3_; s2[3] = fmaf(t3_, t3_, s2[3]); }

__global__ __launch_bounds__(256, 4) void mfmm_te_kernel(
    const unsigned short* __restrict__ A,   // e_bf (permuted order)
    const unsigned short* __restrict__ WT,
    const float* __restrict__ bias,
    const float* __restrict__ Bh, const float* __restrict__ Ch,
    const int* __restrict__ psrc, const int* __restrict__ pdst,
    unsigned short* __restrict__ T,
    float* __restrict__ P)
{
    __shared__ unsigned short sW[128 * SWT_STRIDE];
    const int t = threadIdx.x;
    const int w = t >> 6, lane = t & 63;
    const int q = lane >> 4, n = lane & 15;
    const int row0 = blockIdx.x * 128;

#pragma unroll
    for (int i = 0; i < 8; ++i) {
        int flat = t * 8 + i * 2048;
        int r = flat >> 7, k = flat & 127;
        *(s16x8*)&sW[r * SWT_STRIDE + k] = *(const s16x8*)(WT + flat);
    }
    __syncthreads();

    f32x4 acc[2][8];
#pragma unroll
    for (int tm = 0; tm < 2; ++tm)
#pragma unroll
        for (int tc = 0; tc < 8; ++tc) acc[tm][tc] = (f32x4){0.f, 0.f, 0.f, 0.f};

    const unsigned short* a0p = A + (size_t)(row0 + w * 32 + n) * D + q * 8;

#pragma unroll
    for (int kk = 0; kk < 128; kk += 32) {
        s16x8 af0 = *(const s16x8*)(a0p + kk);
        s16x8 af1 = *(const s16x8*)(a0p + 16 * D + kk);
#pragma unroll
        for (int tc = 0; tc < 8; ++tc) {
            s16x8 bf = *(const s16x8*)&sW[(tc * 16 + n) * SWT_STRIDE + kk + q * 8];
            acc[0][tc] = __builtin_amdgcn_mfma_f32_16x16x32_bf16(af0, bf, acc[0][tc], 0, 0, 0);
            acc[1][tc] = __builtin_amdgcn_mfma_f32_16x16x32_bf16(af1, bf, acc[1][tc], 0, 0, 0);
        }
    }

    float bs[8];
#pragma unroll
    for (int tc = 0; tc < 8; ++tc) bs[tc] = bias[tc * 16 + n];

    // index loads hoisted: latency drains under sync#1 + acc->LDS staging
    const int c4 = (t & 31) * 4;
    const int rg = t >> 5;
    int srs[16], drs[16];
#pragma unroll
    for (int i = 0; i < 16; ++i) {
        int eid = row0 + rg + i * 8;
        srs[i] = psrc[eid];
        drs[i] = pdst[eid];
    }

    __syncthreads();
#pragma unroll
    for (int tm = 0; tm < 2; ++tm)
#pragma unroll
        for (int tc = 0; tc < 8; ++tc)
#pragma unroll
            for (int r = 0; r < 4; ++r) {
                int row = w * 32 + tm * 16 + q * 4 + r;
                int col = tc * 16 + n;
                sW[row * SWT_STRIDE + col] = f2bf(acc[tm][tc][r] + bs[tc]);
            }

    // prefetch gathers 0..3 before the barrier (vmcnt(0) drain completes them)
    TE_GLD(bv0, cv0, 0)
    TE_GLD(bv1, cv1, 1)
    TE_GLD(bv2, cv2, 2)
    TE_GLD(bv3, cv3, 3)
    __syncthreads();

    float s1[4] = {0.f, 0.f, 0.f, 0.f}, s2[4] = {0.f, 0.f, 0.f, 0.f};
    // static 4-deep pipeline: issue load i+4, consume i
    TE_GLD(bv4, cv4, 4)    TE_CONS(bv0, cv0, 0)
    TE_GLD(bv5, cv5, 5)    TE_CONS(bv1, cv1, 1)
    TE_GLD(bv6, cv6, 6)    TE_CONS(bv2, cv2, 2)
    TE_GLD(bv7, cv7, 7)    TE_CONS(bv3, cv3, 3)
    TE_GLD(bv8, cv8, 8)    TE_CONS(bv4, cv4, 4)
    TE_GLD(bv9, cv9, 9)    TE_CONS(bv5, cv5, 5)
    TE_GLD(bv10, cv10, 10) TE_CONS(bv6, cv6, 6)
    TE_GLD(bv11, cv11, 11) TE_CONS(bv7, cv7, 7)
    TE_GLD(bv12, cv12, 12) TE_CONS(bv8, cv8, 8)
    TE_GLD(bv13, cv13, 13) TE_CONS(bv9, cv9, 9)
    TE_GLD(bv14, cv14, 14) TE_CONS(bv10, cv10, 10)
    TE_GLD(bv15, cv15, 15) TE_CONS(bv11, cv11, 11)
    TE_CONS(bv12, cv12, 12)
    TE_CONS(bv13, cv13, 13)
    TE_CONS(bv14, cv14, 14)
    TE_CONS(bv15, cv15, 15)

    __syncthreads();
    float* red = (float*)sW;
#pragma unroll
    for (int j = 0; j < 4; ++j) {
        red[rg * 128 + c4 + j] = s1[j];
        red[1024 + rg * 128 + c4 + j] = s2[j];
    }
    __syncthreads();
    if (t < 128) {
        float a = 0.f, b = 0.f;
#pragma unroll
        for (int g = 0; g < 8; ++g) { a += red[g * 128 + t]; b += red[1024 + g * 128 + t]; }
        P[(size_t)blockIdx.x * 256 + t] = a;
        P[(size_t)blockIdx.x * 256 + 128 + t] = b;
    }
}

// ---------- fused gather agg + apply_e (r6 pair version; layers 0/1 only —
//  layer 2's h-path is dead and its e-update is applied inside mfmm_final)
__global__ __launch_bounds__(256) void agg_apply_kernel(
    unsigned short* E, const unsigned short* __restrict__ T,
    const float* __restrict__ Vh, const float* __restrict__ stats,
    const int* __restrict__ rowptr, const int* __restrict__ pdst,
    const float* __restrict__ inv_cnt, float* __restrict__ Uh)
{
    int n = blockIdx.x * 4 + (threadIdx.x >> 6);
    if (n >= NN) return;
    int lane = threadIdx.x & 63;
    int c2 = lane * 2;
    float2 sc = *(const float2*)(stats + 2 * D + c2);
    float2 sh = *(const float2*)(stats + 3 * D + c2);
    int beg = rowptr[n], end = rowptr[n + 1];
    float a0 = 0.f, a1 = 0.f, b0 = 0.f, b1 = 0.f;

    if (beg < end) {
        const int m = end - 1;
        int jB0 = beg + 1 < m ? beg + 1 : m;
        int jA1 = beg + 2 < m ? beg + 2 : m;
        int jB1 = beg + 3 < m ? beg + 3 : m;
        int gA0 = pdst[beg], gB0 = pdst[jB0];
        int gA1 = pdst[jA1], gB1 = pdst[jB1];
        unsigned int epA0 = *(const unsigned int*)(E + (size_t)beg * D + c2);
        unsigned int epB0 = *(const unsigned int*)(E + (size_t)jB0 * D + c2);
        unsigned int epA1 = *(const unsigned int*)(E + (size_t)jA1 * D + c2);
        unsigned int epB1 = *(const unsigned int*)(E + (size_t)jB1 * D + c2);
        unsigned int tpA0 = *(const unsigned int*)(T + (size_t)beg * D + c2);
        unsigned int tpB0 = *(const unsigned int*)(T + (size_t)jB0 * D + c2);
        unsigned int tpA1 = *(const unsigned int*)(T + (size_t)jA1 * D + c2);
        unsigned int tpB1 = *(const unsigned int*)(T + (size_t)jB1 * D + c2);
        float2 vvA0 = *(const float2*)(Vh + (size_t)gA0 * D + c2);
        float2 vvB0 = *(const float2*)(Vh + (size_t)gB0 * D + c2);

        for (int j = beg; j < end; j += 2) {
            // prefetch pair k+2 (clamped; tail prefetches are discarded)
            int jA2 = j + 4 < m ? j + 4 : m;
            int jB2 = j + 5 < m ? j + 5 : m;
            int gA2 = pdst[jA2], gB2 = pdst[jB2];
            unsigned int epA2 = *(const unsigned int*)(E + (size_t)jA2 * D + c2);
            unsigned int epB2 = *(const unsigned int*)(E + (size_t)jB2 * D + c2);
            unsigned int tpA2 = *(const unsigned int*)(T + (size_t)jA2 * D + c2);
            unsigned int tpB2 = *(const unsigned int*)(T + (size_t)jB2 * D + c2);
            // issue Vh gathers for pair k+1 (indices resolved last iteration)
            float2 vvA1 = *(const float2*)(Vh + (size_t)gA1 * D + c2);
            float2 vvB1 = *(const float2*)(Vh + (size_t)gB1 * D + c2);

            // consume stream A (edge j, always valid)
            float eA0 = bf2f((unsigned short)(epA0 & 0xffff));
            float eA1 = bf2f((unsigned short)(epA0 >> 16));
            a0 = fmaf(sigm_(eA0), vvA0.x, a0);
            a1 = fmaf(sigm_(eA1), vvA0.y, a1);
            float tA0 = bf2f((unsigned short)(tpA0 & 0xffff));
            float tA1 = bf2f((unsigned short)(tpA0 >> 16));
            unsigned short oA0 = f2bf(eA0 + silu_(fmaf(tA0, sc.x, sh.x)));
            unsigned short oA1 = f2bf(eA1 + silu_(fmaf(tA1, sc.y, sh.y)));
            *(unsigned int*)(E + (size_t)j * D + c2) = ((unsigned int)oA1 << 16) | oA0;

            // consume stream B (edge j+1; agg masked if past end; store idempotent)
            float vb = (j + 1 < end) ? 1.f : 0.f;
            int jB = j + 1 < m ? j + 1 : m;
            float eB0 = bf2f((unsigned short)(epB0 & 0xffff));
            float eB1 = bf2f((unsigned short)(epB0 >> 16));
            b0 = fmaf(sigm_(eB0) * vb, vvB0.x, b0);
            b1 = fmaf(sigm_(eB1) * vb, vvB0.y, b1);
            float tB0 = bf2f((unsigned short)(tpB0 & 0xffff));
            float tB1 = bf2f((unsigned short)(tpB0 >> 16));
            unsigned short oB0 = f2bf(eB0 + silu_(fmaf(tB0, sc.x, sh.x)));
            unsigned short oB1 = f2bf(eB1 + silu_(fmaf(tB1, sc.y, sh.y)));
            *(unsigned int*)(E + (size_t)jB * D + c2) = ((unsigned int)oB1 << 16) | oB0;

            // rotate (named scalars)
            epA0 = epA1; epB0 = epB1;
            epA1 = epA2; epB1 = epB2;
            tpA0 = tpA1; tpB0 = tpB1;
            tpA1 = tpA2; tpB1 = tpB2;
            gA1 = gA2; gB1 = gB2;
            vvA0 = vvA1; vvB0 = vvB1;
        }
    }
    float ic = inv_cnt[n];
    size_t o = (size_t)n * D + c2;
    float2 u = *(const float2*)(Uh + o);
    u.x = fmaf(a0 + b0, ic, u.x);
    u.y = fmaf(a1 + b1, ic, u.y);
    *(float2*)(Uh + o) = u;
}

// ---------- E stats: 64-block partial reduce + last-block finalize (fused)
__global__ __launch_bounds__(256) void estats_kernel(
    const float* __restrict__ P, int nblk, float* __restrict__ P2,
    const float* __restrict__ gamma, const float* __restrict__ beta,
    float inv_rows, float* __restrict__ stats, int* __restrict__ counter)
{
    int t = threadIdx.x;
    float s = 0.f;
    for (int j = blockIdx.x; j < nblk; j += gridDim.x)
        s += P[(size_t)j * 256 + t];
    P2[blockIdx.x * 256 + t] = s;
    __threadfence();
    __shared__ int isLast;
    if (t == 0) isLast = (atomicAdd(counter, 1) == (int)gridDim.x - 1);
    __syncthreads();
    if (isLast) {
        if (t == 0) *counter = 0;
        __threadfence_block();
        if (t < 128) {
            float s1 = 0.f, s2 = 0.f;
            for (int j = 0; j < 64; ++j) {
                s1 += P2[j * 256 + t];
                s2 += P2[j * 256 + 128 + t];
            }
            float m = s1 * inv_rows;
            float v = s2 * inv_rows - m * m;
            float rstd = rsqrtf(v + BN_EPS);
            float scv = gamma[t] * rstd;
            stats[2 * D + t] = scv;
            stats[3 * D + t] = beta[t] - m * scv;
        }
    }
}

// ---------- H stats: 20-block column partials + last-block finalize (fused)
__global__ __launch_bounds__(256) void hstats_kernel(
    const float* __restrict__ Th, float* __restrict__ PH,
    const float* __restrict__ gamma, const float* __restrict__ beta,
    float inv_rows, float* __restrict__ stats, int* __restrict__ counter)
{
    __shared__ float red1[8][128], red2[8][128];
    int t = threadIdx.x;
    int c0 = (t & 31) * 4, half = t >> 5;
    int rbase = blockIdx.x * 1024;
    float s1[4] = {0, 0, 0, 0}, s2[4] = {0, 0, 0, 0};
    for (int i = 0; i < 128; ++i) {
        int r = rbase + half + 8 * i;
        if (r >= NN) break;
        float4 v = *(const float4*)(Th + (size_t)r * D + c0);
        s1[0] += v.x; s2[0] = fmaf(v.x, v.x, s2[0]);
        s1[1] += v.y; s2[1] = fmaf(v.y, v.y, s2[1]);
        s1[2] += v.z; s2[2] = fmaf(v.z, v.z, s2[2]);
        s1[3] += v.w; s2[3] = fmaf(v.w, v.w, s2[3]);
    }
#pragma unroll
    for (int j = 0; j < 4; ++j) { red1[half][c0 + j] = s1[j]; red2[half][c0 + j] = s2[j]; }
    __syncthreads();
    if (t < 128) {
        float a = 0.f, b = 0.f;
#pragma unroll
        for (int hh = 0; hh < 8; ++hh) { a += red1[hh][t]; b += red2[hh][t]; }
        PH[(size_t)blockIdx.x * 256 + t] = a;
        PH[(size_t)blockIdx.x * 256 + 128 + t] = b;
    }
    __threadfence();
    __shared__ int isLast;
    if (t == 0) isLast = (atomicAdd(counter, 1) == (int)gridDim.x - 1);
    __syncthreads();
    if (isLast) {
        if (t == 0) *counter = 0;
        __threadfence_block();
        if (t < 128) {
            float a = 0.f, b = 0.f;
            for (int j = 0; j < 20; ++j) {
                a += PH[(size_t)j * 256 + t];
                b += PH[(size_t)j * 256 + 128 + t];
            }
            float m = a * inv_rows;
            float v = b * inv_rows - m * m;
            float rstd = rsqrtf(v + BN_EPS);
            float scv = gamma[t] * rstd;
            stats[2 * D + t] = scv;
            stats[3 * D + t] = beta[t] - m * scv;
        }
    }
}

// ---------- input projections (init_h emits hi/lo too)
__global__ __launch_bounds__(256) void init_h_kernel(
    const float* __restrict__ x, const float* __restrict__ hp_w,
    const float* __restrict__ hp_b, float* __restrict__ h,
    unsigned short* __restrict__ hhi, unsigned short* __restrict__ hlo)
{
    int idx = blockIdx.x * 256 + threadIdx.x;
    int n = idx >> 5, d = (idx & 31) * 4;
    if (n >= NN) return;
    float x0 = x[n * 2], x1 = x[n * 2 + 1];
    float4 w0 = *(const float4*)(hp_w + d);
    float4 w1 = *(const float4*)(hp_w + D + d);
    float4 b = *(const float4*)(hp_b + d);
    float4 o;
    o.x = silu_(fmaf(x0, w0.x, fmaf(x1, w1.x, b.x)));
    o.y = silu_(fmaf(x0, w0.y, fmaf(x1, w1.y, b.y)));
    o.z = silu_(fmaf(x0, w0.z, fmaf(x1, w1.z, b.z)));
    o.w = silu_(fmaf(x0, w0.w, fmaf(x1, w1.w, b.w)));
    *(float4*)(h + (size_t)n * D + d) = o;
    ushort4 hi = make_ushort4(f2bf(o.x), f2bf(o.y), f2bf(o.z), f2bf(o.w));
    ushort4 lo = make_ushort4(f2bf(o.x - bf2f(hi.x)), f2bf(o.y - bf2f(hi.y)),
                              f2bf(o.z - bf2f(hi.z)), f2bf(o.w - bf2f(hi.w)));
    *(ushort4*)(hhi + (size_t)n * D + d) = hi;
    *(ushort4*)(hlo + (size_t)n * D + d) = lo;
}

// init_e in PERMUTED order: row j <- edge eidx[j]
__global__ __launch_bounds__(256) void init_e_kernel(
    const float* __restrict__ ea, const int* __restrict__ eidx,
    const float* __restrict__ ep_w, const float* __restrict__ ep_b,
    unsigned short* __restrict__ e)
{
    int idx = blockIdx.x * 256 + threadIdx.x;
    int j = idx >> 5, d = (idx & 31) * 4;
    if (j >= NE) return;
    float a = ea[eidx[j]];
    float4 w = *(const float4*)(ep_w + d);
    float4 b = *(const float4*)(ep_b + d);
    ushort4 o;
    o.x = f2bf(silu_(fmaf(a, w.x, b.x)));
    o.y = f2bf(silu_(fmaf(a, w.y, b.y)));
    o.z = f2bf(silu_(fmaf(a, w.z, b.z)));
    o.w = f2bf(silu_(fmaf(a, w.w, b.w)));
    *(ushort4*)(e + (size_t)j * D + d) = o;
}

// ---------- CSR build
__global__ __launch_bounds__(256) void deg_kernel(const int* __restrict__ src, int* __restrict__ deg)
{
    int i = blockIdx.x * 256 + threadIdx.x;
    if (i < NE) atomicAdd(&deg[src[i]], 1);
}

__global__ __launch_bounds__(256) void scan_kernel(
    const int* __restrict__ deg, int* __restrict__ rowptr, float* __restrict__ inv_cnt)
{
    __shared__ int chunk[256];
    const int t = threadIdx.x;
    const int CH = (NN + 255) / 256;
    int s = 0;
    for (int i = 0; i < CH; ++i) {
        int idx = t * CH + i;
        if (idx < NN) s += deg[idx];
    }
    chunk[t] = s;
    __syncthreads();
    for (int offs = 1; offs < 256; offs <<= 1) {
        int v = (t >= offs) ? chunk[t - offs] : 0;
        __syncthreads();
        chunk[t] += v;
        __syncthreads();
    }
    int base = (t == 0) ? 0 : chunk[t - 1];
    for (int i = 0; i < CH; ++i) {
        int idx = t * CH + i;
        if (idx < NN) {
            rowptr[idx] = base;
            int d = deg[idx];
            inv_cnt[idx] = 1.0f / fmaxf((float)d, 1.0f);
            base += d;
        }
    }
    if (t == 255) rowptr[NN] = base;
}

__global__ __launch_bounds__(256) void fill_kernel(
    const int* __restrict__ src, const int* __restrict__ dst,
    const int* __restrict__ rowptr, int* __restrict__ cursor,
    int* __restrict__ eidx, int* __restrict__ psrc, int* __restrict__ pdst)
{
    int i = blockIdx.x * 256 + threadIdx.x;
    if (i >= NE) return;
    int s = src[i];
    int p = atomicAdd(&cursor[s], 1);
    int pos = rowptr[s] + p;
    eidx[pos] = i;
    psrc[pos] = s;
    pdst[pos] = dst[i];
}

// h += silu(t_h*sc+sh); also emit h_hi/h_lo for next layer's node matmul
__global__ __launch_bounds__(256) void apply_h_kernel(
    float* __restrict__ h, const float* __restrict__ Th, const float* __restrict__ stats,
    unsigned short* __restrict__ hhi, unsigned short* __restrict__ hlo)
{
    int idx = blockIdx.x * 256 + threadIdx.x;
    int r = idx >> 5, d = (idx & 31) * 4;
    if (r >= NN) return;
    float4 tv = *(const float4*)(Th + (size_t)r * D + d);
    float4 sc = *(const float4*)(stats + 2 * D + d);
    float4 sh = *(const float4*)(stats + 3 * D + d);
    float4 hv = *(const float4*)(h + (size_t)r * D + d);
    hv.x += silu_(fmaf(tv.x, sc.x, sh.x));
    hv.y += silu_(fmaf(tv.y, sc.y, sh.y));
    hv.z += silu_(fmaf(tv.z, sc.z, sh.z));
    hv.w += silu_(fmaf(tv.w, sc.w, sh.w));
    *(float4*)(h + (size_t)r * D + d) = hv;
    ushort4 hi = make_ushort4(f2bf(hv.x), f2bf(hv.y), f2bf(hv.z), f2bf(hv.w));
    ushort4 lo = make_ushort4(f2bf(hv.x - bf2f(hi.x)), f2bf(hv.y - bf2f(hi.y)),
                              f2bf(hv.z - bf2f(hi.z)), f2bf(hv.w - bf2f(hi.w)));
    *(ushort4*)(hhi + (size_t)r * D + d) = hi;
    *(ushort4*)(hlo + (size_t)r * D + d) = lo;
}

extern "C" void kernel_launch(void* const* d_in, const int* in_sizes, int n_in,
                              void* d_out, int out_size, void* d_ws, size_t ws_size,
                              hipStream_t stream)
{
    (void)in_sizes; (void)n_in; (void)out_size;
    const float* x = (const float*)d_in[0];
    const float* edge_attr = (const float*)d_in[1];
    const int* edge_index = (const int*)d_in[2];
    const int* src = edge_index;
    const int* dst = edge_index + NE;
    const float* hp_w = (const float*)d_in[3];
    const float* hp_b = (const float*)d_in[4];
    const float* ep_w = (const float*)d_in[5];
    const float* ep_b = (const float*)d_in[6];
    const float* Uw = (const float*)d_in[7];
    const float* Ub = (const float*)d_in[8];
    const float* Vw = (const float*)d_in[9];
    const float* Vb = (const float*)d_in[10];
    const float* Aw = (const float*)d_in[11];
    const float* Ab = (const float*)d_in[12];
    const float* Bw = (const float*)d_in[13];
    const float* Bb = (const float*)d_in[14];
    const float* Cw = (const float*)d_in[15];
    const float* Cb = (const float*)d_in[16];
    const float* h_gamma = (const float*)d_in[17];
    const float* h_beta = (const float*)d_in[18];
    const float* e_gamma = (const float*)d_in[19];
    const float* e_beta = (const float*)d_in[20];
    const float* f1w = (const float*)d_in[21];
    const float* f1b = (const float*)d_in[22];
    const float* f2w = (const float*)d_in[23];
    const float* f2b = (const float*)d_in[24];
    const float* f3w = (const float*)d_in[25];
    const float* f3b = (const float*)d_in[26];
    float* out = (float*)d_out;

    size_t off = 0;
    auto alloc = [&](size_t nbytes) {
        void* p = (char*)d_ws + off;
        off += ((nbytes + 255) / 256) * 256;
        return p;
    };
    unsigned short* e_bf = (unsigned short*)alloc((size_t)NE * D * 2);
    unsigned short* t_bf = (unsigned short*)alloc((size_t)NE * D * 2);
    float* h  = (float*)alloc((size_t)NN * D * 4);
    unsigned short* h_hi = (unsigned short*)alloc((size_t)NN * D * 2);
    unsigned short* h_lo = (unsigned short*)alloc((size_t)NN * D * 2);
    float* Uh = (float*)alloc((size_t)NN * D * 4);
    float* Vh = (float*)alloc((size_t)NN * D * 4);
    float* Bh = (float*)alloc((size_t)NN * D * 4);
    float* Ch = (float*)alloc((size_t)NN * D * 4);
    int* deg = (int*)alloc(NN * 4);
    int* rowptr = (int*)alloc((NN + 1) * 4);
    int* cursor = (int*)alloc(NN * 4);
    int* eidx = (int*)alloc((size_t)NE * 4);
    int* psrc = (int*)alloc((size_t)NE * 4);
    int* pdst = (int*)alloc((size_t)NE * 4);
    float* inv_cnt = (float*)alloc(NN * 4);
    float* statsH = (float*)alloc(4 * D * 4);
    float* statsE = (float*)alloc(4 * D * 4);
    float* Pstats = (float*)alloc((size_t)(NE / 128) * 256 * 4);
    float* PstatsH = (float*)alloc(20 * 256 * 4);
    float* PE2 = (float*)alloc(64 * 256 * 4);
    unsigned short* wtsNhi = (unsigned short*)alloc((size_t)12 * D * D * 2);
    unsigned short* wtsNlo = (unsigned short*)alloc((size_t)12 * D * D * 2);
    unsigned short* wtsE = (unsigned short*)alloc((size_t)5 * D * D * 2);  // A0,A1,A2,F1,F2
    int* counters = (int*)alloc(2 * 4);

    if (off > ws_size) return;  // diagnostic guard

    const int nodeBlocks32 = (NN * 32 + 255) / 256;  // 2500
    const int edgeBlocks32 = (NE * 32) / 256;        // 40000
    const int nodeTiles = (NN + 127) / 128;          // 157
    const int edgeTiles = NE / 128;                  // 2500
    const int hBlocks = (NN + 1023) / 1024;          // 20

    // CSR build (needed before permuted init_e)
    hipMemsetAsync(deg, 0, NN * sizeof(int), stream);
    hipMemsetAsync(cursor, 0, NN * sizeof(int), stream);
    hipMemsetAsync(counters, 0, 2 * sizeof(int), stream);
    deg_kernel<<<NE / 256, 256, 0, stream>>>(src, deg);
    scan_kernel<<<1, 256, 0, stream>>>(deg, rowptr, inv_cnt);
    fill_kernel<<<NE / 256, 256, 0, stream>>>(src, dst, rowptr, cursor, eidx, psrc, pdst);

    init_h_kernel<<<nodeBlocks32, 256, 0, stream>>>(x, hp_w, hp_b, h, h_hi, h_lo);
    init_e_kernel<<<edgeBlocks32, 256, 0, stream>>>(edge_attr, eidx, ep_w, ep_b, e_bf);

    // all 17 weight conversions in one dispatch
    ConvJobs cj;
    const float* nodeW[4][3] = {{Uw, Uw + 16384, Uw + 32768},
                                {Vw, Vw + 16384, Vw + 32768},
                                {Bw, Bw + 16384, Bw + 32768},
                                {Cw, Cw + 16384, Cw + 32768}};
    for (int l = 0; l < LAYERS; ++l)
        for (int j = 0; j < 4; ++j) {
            int slot = l * 4 + j;
            cj.W[slot] = nodeW[j][l];
            cj.Hi[slot] = wtsNhi + (size_t)slot * D * D;
            cj.Lo[slot] = wtsNlo + (size_t)slot * D * D;
        }
    const float* edgeW[5] = {Aw, Aw + 16384, Aw + 32768, f1w, f2w};
    for (int j = 0; j < 5; ++j) {
        cj.W[12 + j] = edgeW[j];
        cj.Hi[12 + j] = wtsE + (size_t)j * D * D;
        cj.Lo[12 + j] = nullptr;
    }
    conv_all_kernel<<<dim3(64, 17), 256, 0, stream>>>(cj);

    for (int l = 0; l < LAYERS; ++l) {
        const size_t bl = (size_t)l * D;
        const bool last = (l == LAYERS - 1);

        MatsB2 m4;
        int nmats;
        if (!last) {
            nmats = 4;
            for (int j = 0; j < 4; ++j) {
                size_t slot = (size_t)(l * 4 + j) * D * D;
                m4.WThi[j] = wtsNhi + slot;
                m4.WTlo[j] = wtsNlo + slot;
            }
            m4.b[0] = Ub + bl; m4.b[1] = Vb + bl; m4.b[2] = Bb + bl; m4.b[3] = Cb + bl;
            m4.C[0] = Uh; m4.C[1] = Vh; m4.C[2] = Bh; m4.C[3] = Ch;
        } else {
            // layer 2: h-path is dead — only B,C mats feed t_e -> output
            nmats = 2;
            size_t slotB = (size_t)(l * 4 + 2) * D * D;
            size_t slotC = (size_t)(l * 4 + 3) * D * D;
            m4.WThi[0] = wtsNhi + slotB; m4.WTlo[0] = wtsNlo + slotB;
            m4.WThi[1] = wtsNhi + slotC; m4.WTlo[1] = wtsNlo + slotC;
            m4.WThi[2] = m4.WThi[0]; m4.WTlo[2] = m4.WTlo[0];
            m4.WThi[3] = m4.WThi[1]; m4.WTlo[3] = m4.WTlo[1];
            m4.b[0] = Bb + bl; m4.b[1] = Cb + bl; m4.b[2] = m4.b[0]; m4.b[3] = m4.b[1];
            m4.C[0] = Bh; m4.C[1] = Ch; m4.C[2] = Bh; m4.C[3] = Ch;
        }
        mfmm_node_kernel<<<dim3(nodeTiles, nmats), 256, 0, stream>>>(h_hi, h_lo, NN, m4);

        // t_e matmul + gathers + stat partials
        mfmm_te_kernel<<<edgeTiles, 256, 0, stream>>>(
            e_bf, wtsE + (size_t)l * D * D, Ab + bl, Bh, Ch, psrc, pdst, t_bf, Pstats);

        // e stats: partial reduce + fused finalize (last-block pattern)
        estats_kernel<<<64, 256, 0, stream>>>(Pstats, edgeTiles, PE2,
                                              e_gamma + bl, e_beta + bl,
                                              1.0f / NE, statsE, counters + 0);

        if (!last) {
            // fused aggregation + e-update
            agg_apply_kernel<<<(NN + 3) / 4, 256, 0, stream>>>(
                e_bf, t_bf, Vh, statsE, rowptr, pdst, inv_cnt, Uh);

            // h stats: column partials + fused finalize (last-block pattern)
            hstats_kernel<<<hBlocks, 256, 0, stream>>>(Uh, PstatsH,
                                                       h_gamma + bl, h_beta + bl,
                                                       1.0f / NN, statsH, counters + 1);
            apply_h_kernel<<<nodeBlocks32, 256, 0, stream>>>(h, Uh, statsH, h_hi, h_lo);
        }
        // layer 2: agg/hstats/apply_h are dead (h never read again);
        // the e-update is applied on the fly inside mfmm_final
    }

    // fused final MLP: applies layer-2 e-update on the fly, then f1+f2+f3
    mfmm_final_kernel<<<edgeTiles, 256, 0, stream>>>(
        e_bf, t_bf, statsE,
        wtsE + (size_t)3 * D * D, f1b,
        wtsE + (size_t)4 * D * D, f2b,
        f3w, f3b, out, eidx);
}